// Round 2
// baseline (645.931 us; speedup 1.0000x reference)
//
#include <hip/hip_runtime.h>
#include <stdint.h>

#define DIM 1024
#define NH  16
#define HD  64
#define BB  4
#define TT  4096
#define BT  (BB*TT)   // 16384
#define NC  32        // number of chunks
#define CL  128       // chunk length

typedef __bf16 bf16x8 __attribute__((ext_vector_type(8)));
typedef float  f32x4  __attribute__((ext_vector_type(4)));

__device__ __forceinline__ float bfu(unsigned int u) {
    return __uint_as_float((u & 0xffffu) << 16);
}
__device__ __forceinline__ unsigned short f2bf(float f) {
    unsigned int u = __float_as_uint(f);
    u += 0x7fffu + ((u >> 16) & 1u);
    return (unsigned short)(u >> 16);
}

__device__ __forceinline__ void gload16(const void* g, void* lds) {
    __builtin_amdgcn_global_load_lds((__attribute__((address_space(1))) void*)g,
                                     (__attribute__((address_space(3))) void*)lds,
                                     16, 0, 0);
}

// ---------------- elementwise converters ----------------

__global__ __launch_bounds__(256) void conv_x_kernel(
    const float* __restrict__ x, const float* __restrict__ tmix,
    unsigned short* __restrict__ xx)
{
    int gid = blockIdx.x * 256 + threadIdx.x;          // 4 elems per thread
    float4 xv = ((const float4*)x)[gid];
    float4 tv = ((const float4*)tmix)[gid & 255];
    uint2 o;
    o.x = (unsigned)f2bf(xv.x * tv.x) | ((unsigned)f2bf(xv.y * tv.y) << 16);
    o.y = (unsigned)f2bf(xv.z * tv.z) | ((unsigned)f2bf(xv.w * tv.w) << 16);
    ((uint2*)xx)[gid] = o;
}

__global__ __launch_bounds__(256) void conv_w_kernel(
    const float* __restrict__ Wk, const float* __restrict__ Wv,
    const float* __restrict__ Wr, const float* __restrict__ Wg,
    const float* __restrict__ Wo,
    unsigned short* __restrict__ wcat, unsigned short* __restrict__ wob)
{
    int gid = blockIdx.x * 256 + threadIdx.x;          // 0..1310719
    size_t idx = (size_t)gid * 4;
    float4 v;
    unsigned short* dst;
    if (idx < 4194304) {
        int p = (int)(idx >> 20);
        size_t loc = idx & 1048575;
        const float* src = (p == 0) ? Wk : (p == 1) ? Wv : (p == 2) ? Wr : Wg;
        v = ((const float4*)src)[loc >> 2];
        dst = wcat + idx;
    } else {
        size_t loc = idx - 4194304;
        v = ((const float4*)Wo)[loc >> 2];
        dst = wob + loc;
    }
    uint2 o;
    o.x = (unsigned)f2bf(v.x) | ((unsigned)f2bf(v.y) << 16);
    o.y = (unsigned)f2bf(v.z) | ((unsigned)f2bf(v.w) << 16);
    *(uint2*)dst = o;
}

// rg_merge: rb[i] = rb[i] * gb[i]  (g already has silu applied), in-place on rb
__global__ __launch_bounds__(256) void rg_merge(
    unsigned short* __restrict__ rb, const unsigned short* __restrict__ gb)
{
    int gid = blockIdx.x * 256 + threadIdx.x;          // 4 bf16 per thread
    uint2 rv = ((const uint2*)rb)[gid];
    uint2 gv = ((const uint2*)gb)[gid];
    uint2 o;
    o.x = (unsigned)f2bf(bfu(rv.x) * bfu(gv.x)) |
          ((unsigned)f2bf(bfu(rv.x >> 16) * bfu(gv.x >> 16)) << 16);
    o.y = (unsigned)f2bf(bfu(rv.y) * bfu(gv.y)) |
          ((unsigned)f2bf(bfu(rv.y >> 16) * bfu(gv.y >> 16)) << 16);
    ((uint2*)rb)[gid] = o;
}

// ---------------- bf16 MFMA GEMM (A[M,K] * B[N,K]^T) ----------------

template<int EPI>
__global__ __launch_bounds__(256) void gemm_bt(
    const unsigned short* __restrict__ A, const unsigned short* __restrict__ B,
    float* __restrict__ C, int M, int N, int K,
    unsigned short* __restrict__ kb, unsigned short* __restrict__ vb,
    unsigned short* __restrict__ rb, unsigned short* __restrict__ gb)
{
    __shared__ unsigned short As[128 * 32];
    __shared__ unsigned short Bs[128 * 32];
    const int tid  = threadIdx.x;
    const int w    = tid >> 6;
    const int l    = tid & 63;
    const int srow = l >> 2;
    const int scol = (l & 3) * 8;
    const int lrow = l & 15;
    const int lk8  = (l >> 4) * 8;
    const int wr   = (w >> 1) * 64;
    const int wc   = (w & 1) * 64;
    const size_t bm = (size_t)blockIdx.y * 128;
    const size_t bn = (size_t)blockIdx.x * 128;

    const unsigned short* Ab = A + (bm + w * 16 + srow) * (size_t)K + scol;
    const unsigned short* Bb = B + (bn + w * 16 + srow) * (size_t)K + scol;

    f32x4 acc[4][4] = {};

    for (int k0 = 0; k0 < K; k0 += 32) {
        gload16(Ab + k0,                   &As[(w * 16) * 32]);
        gload16(Ab + k0 + (size_t)64 * K,  &As[(64 + w * 16) * 32]);
        gload16(Bb + k0,                   &Bs[(w * 16) * 32]);
        gload16(Bb + k0 + (size_t)64 * K,  &Bs[(64 + w * 16) * 32]);
        __syncthreads();
        bf16x8 af[4], bfr[4];
        #pragma unroll
        for (int mi = 0; mi < 4; mi++)
            af[mi] = *(const bf16x8*)&As[(wr + mi * 16 + lrow) * 32 + lk8];
        #pragma unroll
        for (int ni = 0; ni < 4; ni++)
            bfr[ni] = *(const bf16x8*)&Bs[(wc + ni * 16 + lrow) * 32 + lk8];
        #pragma unroll
        for (int mi = 0; mi < 4; mi++)
            #pragma unroll
            for (int ni = 0; ni < 4; ni++)
                acc[mi][ni] = __builtin_amdgcn_mfma_f32_16x16x32_bf16(
                    af[mi], bfr[ni], acc[mi][ni], 0, 0, 0);
        __syncthreads();
    }

    const int colb = (int)bn + wc + lrow;
    const int rowb = (int)bm + wr + (l >> 4) * 4;
    if (EPI == 0) {
        const int p = colb >> 10;   // uniform per block
        unsigned short* dst = (p == 0) ? kb : (p == 1) ? vb : (p == 2) ? rb : gb;
        #pragma unroll
        for (int mi = 0; mi < 4; mi++) {
            #pragma unroll
            for (int ni = 0; ni < 4; ni++) {
                const int col = colb + ni * 16;
                const int e = col & 1023;
                const int h = e >> 6, j = e & 63;
                #pragma unroll
                for (int ri = 0; ri < 4; ri++) {
                    const int m = rowb + mi * 16 + ri;
                    const int b = m >> 12, t = m & 4095;
                    float v = acc[mi][ni][ri];
                    if (p == 3) v = v / (1.f + __expf(-v));  // silu
                    dst[(((size_t)(b * NH + h)) * TT + t) * HD + j] = f2bf(v);
                }
            }
        }
    } else {
        #pragma unroll
        for (int mi = 0; mi < 4; mi++)
            #pragma unroll
            for (int ni = 0; ni < 4; ni++)
                #pragma unroll
                for (int ri = 0; ri < 4; ri++)
                    C[(size_t)(rowb + mi * 16 + ri) * N + colb + ni * 16] =
                        acc[mi][ni][ri];
    }
}

// ---------------- recurrence: per-chunk contribution ----------------
// block = bh*NC + c, 64 threads (lane j = v-column).
// contrib[bid][kk*64+j] = sum_s d[kk]^(CL-1-s) k_s[kk] v_s[j]

__global__ __launch_bounds__(64) void chunk_contrib(
    const unsigned short* __restrict__ kb, const unsigned short* __restrict__ vb,
    const float* __restrict__ td, float* __restrict__ contrib)
{
    const int bid = blockIdx.x;
    const int c   = bid & (NC - 1);
    const int bh  = bid >> 5;
    const int h   = bh & (NH - 1);
    const int j   = threadIdx.x;

    __shared__ float          kf[CL][HD];
    __shared__ unsigned short vs[CL][HD];
    __shared__ float          dsh[HD];

    const uint4* ks4 = (const uint4*)(kb + (((size_t)bh * TT) + c * CL) * HD);
    const uint4* vs4 = (const uint4*)(vb + (((size_t)bh * TT) + c * CL) * HD);
    #pragma unroll
    for (int it = 0; it < CL / 8; ++it) {
        int ci = it * 64 + j;
        uint4 r = ks4[ci];
        int row = ci >> 3, cb2 = (ci & 7) * 8;
        f32x4 lo = { bfu(r.x), bfu(r.x >> 16), bfu(r.y), bfu(r.y >> 16) };
        f32x4 hi = { bfu(r.z), bfu(r.z >> 16), bfu(r.w), bfu(r.w >> 16) };
        *(f32x4*)&kf[row][cb2]     = lo;
        *(f32x4*)&kf[row][cb2 + 4] = hi;
        ((uint4*)vs)[ci] = vs4[ci];
    }
    dsh[j] = __expf(-td[h * HD + j]);
    __syncthreads();

    float dreg[HD], st[HD];
    #pragma unroll
    for (int kk = 0; kk < HD; kk++) { dreg[kk] = dsh[kk]; st[kk] = 0.f; }

    for (int i = 0; i < CL; i++) {
        const float vv = bfu(vs[i][j]);
        #pragma unroll
        for (int kq = 0; kq < 16; kq++) {
            f32x4 kv = *(const f32x4*)&kf[i][kq * 4];
            st[kq*4+0] = __builtin_fmaf(dreg[kq*4+0], st[kq*4+0], kv.x * vv);
            st[kq*4+1] = __builtin_fmaf(dreg[kq*4+1], st[kq*4+1], kv.y * vv);
            st[kq*4+2] = __builtin_fmaf(dreg[kq*4+2], st[kq*4+2], kv.z * vv);
            st[kq*4+3] = __builtin_fmaf(dreg[kq*4+3], st[kq*4+3], kv.w * vv);
        }
    }
    float* cb = contrib + (size_t)bid * 4096;
    #pragma unroll
    for (int kk = 0; kk < HD; kk++) cb[kk * 64 + j] = st[kk];
}

// ---------------- recurrence: chunk-level scan (elementwise) ----------------

__global__ __launch_bounds__(256) void chunk_scan(
    float* __restrict__ contrib, const float* __restrict__ td,
    float* __restrict__ state_out)
{
    int gtid = blockIdx.x * 256 + threadIdx.x;   // 0..262143
    int j  = gtid & 63;
    int kk = (gtid >> 6) & 63;
    int bh = gtid >> 12;
    int h  = bh & (NH - 1);
    float dC = __expf(-(float)CL * td[h * HD + kk]);  // d^CL
    float S = 0.f;
    float* base = contrib + ((size_t)bh * NC) * 4096 + kk * 64 + j;
    for (int c = 0; c < NC; c++) {
        float t = base[(size_t)c * 4096];
        base[(size_t)c * 4096] = S;
        S = __builtin_fmaf(dC, S, t);
    }
    state_out[(size_t)bh * 4096 + kk * 64 + j] = S;
}

// ---------------- recurrence: per-chunk output replay ----------------
// rgb holds r*silu(g) merged (bf16).

__global__ __launch_bounds__(64) void chunk_out(
    const unsigned short* __restrict__ kb, const unsigned short* __restrict__ vb,
    const unsigned short* __restrict__ rgb,
    const float* __restrict__ td, const float* __restrict__ tf,
    const float* __restrict__ S0, unsigned short* __restrict__ outp)
{
    const int bid = blockIdx.x;
    const int c   = bid & (NC - 1);
    const int bh  = bid >> 5;
    const int h   = bh & (NH - 1);
    const int b   = bh >> 4;
    const int j   = threadIdx.x;

    __shared__ float          kf[CL][HD];
    __shared__ unsigned short vs[CL][HD];
    __shared__ float          dsh[HD];

    const uint4* ks4 = (const uint4*)(kb + (((size_t)bh * TT) + c * CL) * HD);
    const uint4* vs4 = (const uint4*)(vb + (((size_t)bh * TT) + c * CL) * HD);
    #pragma unroll
    for (int it = 0; it < CL / 8; ++it) {
        int ci = it * 64 + j;
        uint4 r = ks4[ci];
        int row = ci >> 3, cb2 = (ci & 7) * 8;
        f32x4 lo = { bfu(r.x), bfu(r.x >> 16), bfu(r.y), bfu(r.y >> 16) };
        f32x4 hi = { bfu(r.z), bfu(r.z >> 16), bfu(r.w), bfu(r.w >> 16) };
        *(f32x4*)&kf[row][cb2]     = lo;
        *(f32x4*)&kf[row][cb2 + 4] = hi;
        ((uint4*)vs)[ci] = vs4[ci];
    }
    dsh[j] = __expf(-td[h * HD + j]);
    const float tfj = tf[h * HD + j];
    __syncthreads();

    float dreg[HD], st[HD];
    #pragma unroll
    for (int kk = 0; kk < HD; kk++) {
        dreg[kk] = dsh[kk];
        st[kk] = S0[(size_t)bid * 4096 + kk * 64 + j];
    }

    const unsigned short* rrow = rgb + ((size_t)bh * TT + c * CL) * HD + j;
    unsigned short*       orow = outp + ((size_t)b * TT + c * CL) * DIM + h * HD + j;

    for (int i = 0; i < CL; i++) {
        const float vv = bfu(vs[i][j]);
        const float kj = kf[i][j];
        float a0 = 0.f, a1 = 0.f, a2 = 0.f, a3 = 0.f;
        #pragma unroll
        for (int kq = 0; kq < 16; kq++) {
            f32x4 kv = *(const f32x4*)&kf[i][kq * 4];
            float s0 = __builtin_fmaf(dreg[kq*4+0], st[kq*4+0], kv.x * vv);
            float s1 = __builtin_fmaf(dreg[kq*4+1], st[kq*4+1], kv.y * vv);
            float s2 = __builtin_fmaf(dreg[kq*4+2], st[kq*4+2], kv.z * vv);
            float s3 = __builtin_fmaf(dreg[kq*4+3], st[kq*4+3], kv.w * vv);
            st[kq*4+0] = s0; st[kq*4+1] = s1; st[kq*4+2] = s2; st[kq*4+3] = s3;
            a0 = __builtin_fmaf(kv.x, s0, a0);
            a1 = __builtin_fmaf(kv.y, s1, a1);
            a2 = __builtin_fmaf(kv.z, s2, a2);
            a3 = __builtin_fmaf(kv.w, s3, a3);
        }
        float wkv = (a0 + a1) + (a2 + a3) + tfj * kj * vv;
        float rr = bfu(rrow[(size_t)i * HD]);
        orow[(size_t)i * DIM] = f2bf(rr * wkv);
    }
}

// ---------------- launch ----------------
// Workspace map (bytes), peak 170 MB:
//   [0,32M)      xx (bf16)       -> reused as outp (bf16) after gemm1
//   [32M,40M)    wcat (bf16)
//   [40M,42M)    wob (bf16)
//   [42M,74M)    kb
//   [74M,106M)   vb
//   [106M,138M)  rb (-> r*silu(g) after rg_merge)
//   [138M,170M)  gb (bf16) -> reused as ctr (f32, 32MB) after rg_merge

static const size_t OFF_XX   = 0;
static const size_t OFF_WCAT = 33554432;
static const size_t OFF_WO   = 41943040;
static const size_t OFF_K    = 44040192;
static const size_t OFF_V    = 77594624;
static const size_t OFF_R    = 111149056;
static const size_t OFF_G    = 144703488;   // also ctr
static const size_t OFF_OP   = 0;           // aliases xx

extern "C" void kernel_launch(void* const* d_in, const int* in_sizes, int n_in,
                              void* d_out, int out_size, void* d_ws, size_t ws_size,
                              hipStream_t stream) {
    const float* x   = (const float*)d_in[0];
    const float* tmx = (const float*)d_in[1];
    const float* td  = (const float*)d_in[2];
    const float* tf  = (const float*)d_in[3];
    const float* Wk  = (const float*)d_in[4];
    const float* Wv  = (const float*)d_in[5];
    const float* Wr  = (const float*)d_in[6];
    const float* Wg  = (const float*)d_in[7];
    const float* Wo  = (const float*)d_in[8];

    char* ws = (char*)d_ws;
    unsigned short* xx   = (unsigned short*)(ws + OFF_XX);
    unsigned short* wcat = (unsigned short*)(ws + OFF_WCAT);
    unsigned short* wob  = (unsigned short*)(ws + OFF_WO);
    unsigned short* kb   = (unsigned short*)(ws + OFF_K);
    unsigned short* vb   = (unsigned short*)(ws + OFF_V);
    unsigned short* rb   = (unsigned short*)(ws + OFF_R);
    unsigned short* gb   = (unsigned short*)(ws + OFF_G);
    float*          ctr  = (float*)(ws + OFF_G);
    unsigned short* outp = (unsigned short*)(ws + OFF_OP);

    float* out       = (float*)d_out;
    float* state_out = out + (size_t)BT * DIM;

    conv_x_kernel<<<16384, 256, 0, stream>>>(x, tmx, xx);
    conv_w_kernel<<<5120, 256, 0, stream>>>(Wk, Wv, Wr, Wg, Wo, wcat, wob);
    gemm_bt<0><<<dim3(32, 128), 256, 0, stream>>>(xx, wcat, nullptr,
                                                  BT, 4096, 1024, kb, vb, rb, gb);
    rg_merge<<<16384, 256, 0, stream>>>(rb, gb);
    chunk_contrib<<<64 * NC, 64, 0, stream>>>(kb, vb, td, ctr);
    chunk_scan<<<1024, 256, 0, stream>>>(ctr, td, state_out);
    chunk_out<<<64 * NC, 64, 0, stream>>>(kb, vb, rb, td, tf, ctr, outp);
    gemm_bt<1><<<dim3(8, 128), 256, 0, stream>>>(outp, wob, out,
                                                 BT, 1024, 1024,
                                                 nullptr, nullptr, nullptr, nullptr);
}

// Round 3
// 570.261 us; speedup vs baseline: 1.1327x; 1.1327x over previous
//
#include <hip/hip_runtime.h>
#include <stdint.h>

#define DIM 1024
#define NH  16
#define HD  64
#define BB  4
#define TT  4096
#define BT  (BB*TT)   // 16384
#define NC  32        // number of chunks
#define CL  128       // chunk length

typedef __bf16 bf16x8 __attribute__((ext_vector_type(8)));
typedef float  f32x4  __attribute__((ext_vector_type(4)));

__device__ __forceinline__ float bfu(unsigned int u) {
    return __uint_as_float((u & 0xffffu) << 16);
}
__device__ __forceinline__ unsigned short f2bf(float f) {
    unsigned int u = __float_as_uint(f);
    u += 0x7fffu + ((u >> 16) & 1u);
    return (unsigned short)(u >> 16);
}

__device__ __forceinline__ void gload16(const void* g, void* lds) {
    __builtin_amdgcn_global_load_lds((__attribute__((address_space(1))) void*)g,
                                     (__attribute__((address_space(3))) void*)lds,
                                     16, 0, 0);
}

// ---------------- elementwise converters ----------------

__global__ __launch_bounds__(256) void conv_x_kernel(
    const float* __restrict__ x, const float* __restrict__ tmix,
    unsigned short* __restrict__ xx)
{
    int gid = blockIdx.x * 256 + threadIdx.x;          // 4 elems per thread
    float4 xv = ((const float4*)x)[gid];
    float4 tv = ((const float4*)tmix)[gid & 255];
    uint2 o;
    o.x = (unsigned)f2bf(xv.x * tv.x) | ((unsigned)f2bf(xv.y * tv.y) << 16);
    o.y = (unsigned)f2bf(xv.z * tv.z) | ((unsigned)f2bf(xv.w * tv.w) << 16);
    ((uint2*)xx)[gid] = o;
}

__global__ __launch_bounds__(256) void conv_w_kernel(
    const float* __restrict__ Wk, const float* __restrict__ Wv,
    const float* __restrict__ Wr, const float* __restrict__ Wg,
    const float* __restrict__ Wo,
    unsigned short* __restrict__ wcat, unsigned short* __restrict__ wob)
{
    int gid = blockIdx.x * 256 + threadIdx.x;          // 0..1310719
    size_t idx = (size_t)gid * 4;
    float4 v;
    unsigned short* dst;
    if (idx < 4194304) {
        int p = (int)(idx >> 20);
        size_t loc = idx & 1048575;
        const float* src = (p == 0) ? Wk : (p == 1) ? Wv : (p == 2) ? Wr : Wg;
        v = ((const float4*)src)[loc >> 2];
        dst = wcat + idx;
    } else {
        size_t loc = idx - 4194304;
        v = ((const float4*)Wo)[loc >> 2];
        dst = wob + loc;
    }
    uint2 o;
    o.x = (unsigned)f2bf(v.x) | ((unsigned)f2bf(v.y) << 16);
    o.y = (unsigned)f2bf(v.z) | ((unsigned)f2bf(v.w) << 16);
    *(uint2*)dst = o;
}

// rg_merge: rb[i] = rb[i] * gb[i]  (g already has silu applied), in-place on rb
__global__ __launch_bounds__(256) void rg_merge(
    unsigned short* __restrict__ rb, const unsigned short* __restrict__ gb)
{
    int gid = blockIdx.x * 256 + threadIdx.x;          // 4 bf16 per thread
    uint2 rv = ((const uint2*)rb)[gid];
    uint2 gv = ((const uint2*)gb)[gid];
    uint2 o;
    o.x = (unsigned)f2bf(bfu(rv.x) * bfu(gv.x)) |
          ((unsigned)f2bf(bfu(rv.x >> 16) * bfu(gv.x >> 16)) << 16);
    o.y = (unsigned)f2bf(bfu(rv.y) * bfu(gv.y)) |
          ((unsigned)f2bf(bfu(rv.y >> 16) * bfu(gv.y >> 16)) << 16);
    ((uint2*)rb)[gid] = o;
}

// ---------------- bf16 MFMA GEMM (A[M,K] * B[N,K]^T) ----------------

template<int EPI>
__global__ __launch_bounds__(256) void gemm_bt(
    const unsigned short* __restrict__ A, const unsigned short* __restrict__ B,
    float* __restrict__ C, int M, int N, int K,
    unsigned short* __restrict__ kb, unsigned short* __restrict__ vb,
    unsigned short* __restrict__ rb, unsigned short* __restrict__ gb)
{
    __shared__ unsigned short As[128 * 32];
    __shared__ unsigned short Bs[128 * 32];
    const int tid  = threadIdx.x;
    const int w    = tid >> 6;
    const int l    = tid & 63;
    const int srow = l >> 2;
    const int scol = (l & 3) * 8;
    const int lrow = l & 15;
    const int lk8  = (l >> 4) * 8;
    const int wr   = (w >> 1) * 64;
    const int wc   = (w & 1) * 64;
    const size_t bm = (size_t)blockIdx.y * 128;
    const size_t bn = (size_t)blockIdx.x * 128;

    const unsigned short* Ab = A + (bm + w * 16 + srow) * (size_t)K + scol;
    const unsigned short* Bb = B + (bn + w * 16 + srow) * (size_t)K + scol;

    f32x4 acc[4][4] = {};

    for (int k0 = 0; k0 < K; k0 += 32) {
        gload16(Ab + k0,                   &As[(w * 16) * 32]);
        gload16(Ab + k0 + (size_t)64 * K,  &As[(64 + w * 16) * 32]);
        gload16(Bb + k0,                   &Bs[(w * 16) * 32]);
        gload16(Bb + k0 + (size_t)64 * K,  &Bs[(64 + w * 16) * 32]);
        __syncthreads();
        bf16x8 af[4], bfr[4];
        #pragma unroll
        for (int mi = 0; mi < 4; mi++)
            af[mi] = *(const bf16x8*)&As[(wr + mi * 16 + lrow) * 32 + lk8];
        #pragma unroll
        for (int ni = 0; ni < 4; ni++)
            bfr[ni] = *(const bf16x8*)&Bs[(wc + ni * 16 + lrow) * 32 + lk8];
        #pragma unroll
        for (int mi = 0; mi < 4; mi++)
            #pragma unroll
            for (int ni = 0; ni < 4; ni++)
                acc[mi][ni] = __builtin_amdgcn_mfma_f32_16x16x32_bf16(
                    af[mi], bfr[ni], acc[mi][ni], 0, 0, 0);
        __syncthreads();
    }

    const int colb = (int)bn + wc + lrow;
    const int rowb = (int)bm + wr + (l >> 4) * 4;
    if (EPI == 0) {
        const int p = colb >> 10;   // uniform per block
        unsigned short* dst = (p == 0) ? kb : (p == 1) ? vb : (p == 2) ? rb : gb;
        #pragma unroll
        for (int mi = 0; mi < 4; mi++) {
            #pragma unroll
            for (int ni = 0; ni < 4; ni++) {
                const int col = colb + ni * 16;
                const int e = col & 1023;
                const int h = e >> 6, j = e & 63;
                #pragma unroll
                for (int ri = 0; ri < 4; ri++) {
                    const int m = rowb + mi * 16 + ri;
                    const int b = m >> 12, t = m & 4095;
                    float v = acc[mi][ni][ri];
                    if (p == 3) v = v / (1.f + __expf(-v));  // silu
                    dst[(((size_t)(b * NH + h)) * TT + t) * HD + j] = f2bf(v);
                }
            }
        }
    } else {
        #pragma unroll
        for (int mi = 0; mi < 4; mi++)
            #pragma unroll
            for (int ni = 0; ni < 4; ni++)
                #pragma unroll
                for (int ri = 0; ri < 4; ri++)
                    C[(size_t)(rowb + mi * 16 + ri) * N + colb + ni * 16] =
                        acc[mi][ni][ri];
    }
}

// ---------------- recurrence (4-wave-per-chunk layout) ----------------
// Block = 256 threads = one (b,h,chunk). thread -> (j = tid>>2, kg = tid&3).
// Thread owns st[16] = state rows k in [16*kg,16*kg+16), column v=j.
// Output reduce over kg via shfl_xor(1),shfl_xor(2) within the 4-lane group.

__global__ __launch_bounds__(256) void chunk_contrib(
    const unsigned short* __restrict__ kb, const unsigned short* __restrict__ vb,
    const float* __restrict__ td, float* __restrict__ contrib)
{
    const int bid = blockIdx.x;
    const int c   = bid & (NC - 1);
    const int bh  = bid >> 5;
    const int h   = bh & (NH - 1);
    const int tid = threadIdx.x;
    const int j   = tid >> 2;
    const int kg  = tid & 3;

    __shared__ float          kf[CL][HD];   // 32KB
    __shared__ unsigned short vs[CL][HD];   // 16KB

    const uint4* ks4 = (const uint4*)(kb + (((size_t)bh * TT) + c * CL) * HD);
    const uint4* vs4 = (const uint4*)(vb + (((size_t)bh * TT) + c * CL) * HD);
    #pragma unroll
    for (int it = 0; it < 4; ++it) {
        int ci = it * 256 + tid;             // 0..1023 uint4s
        uint4 r = ks4[ci];
        int row = ci >> 3, cb2 = (ci & 7) * 8;
        f32x4 lo = { bfu(r.x), bfu(r.x >> 16), bfu(r.y), bfu(r.y >> 16) };
        f32x4 hi = { bfu(r.z), bfu(r.z >> 16), bfu(r.w), bfu(r.w >> 16) };
        *(f32x4*)&kf[row][cb2]     = lo;
        *(f32x4*)&kf[row][cb2 + 4] = hi;
        ((uint4*)vs)[ci] = vs4[ci];
    }
    float dreg[16], st[16];
    #pragma unroll
    for (int kk = 0; kk < 16; kk++) {
        dreg[kk] = __expf(-td[h * HD + kg * 16 + kk]);
        st[kk] = 0.f;
    }
    __syncthreads();

    for (int i = 0; i < CL; i++) {
        const float vv = bfu(vs[i][j]);
        const float* krow = &kf[i][kg * 16];
        #pragma unroll
        for (int q = 0; q < 4; q++) {
            f32x4 kv = *(const f32x4*)&krow[q * 4];
            st[q*4+0] = __builtin_fmaf(dreg[q*4+0], st[q*4+0], kv.x * vv);
            st[q*4+1] = __builtin_fmaf(dreg[q*4+1], st[q*4+1], kv.y * vv);
            st[q*4+2] = __builtin_fmaf(dreg[q*4+2], st[q*4+2], kv.z * vv);
            st[q*4+3] = __builtin_fmaf(dreg[q*4+3], st[q*4+3], kv.w * vv);
        }
    }
    float* cb = contrib + (size_t)bid * 4096 + (kg * 16) * 64 + j;
    #pragma unroll
    for (int kk = 0; kk < 16; kk++) cb[kk * 64] = st[kk];
}

// ---------------- recurrence: chunk-level scan (elementwise) ----------------

__global__ __launch_bounds__(256) void chunk_scan(
    float* __restrict__ contrib, const float* __restrict__ td,
    float* __restrict__ state_out)
{
    int gtid = blockIdx.x * 256 + threadIdx.x;   // 0..262143
    int j  = gtid & 63;
    int kk = (gtid >> 6) & 63;
    int bh = gtid >> 12;
    int h  = bh & (NH - 1);
    float dC = __expf(-(float)CL * td[h * HD + kk]);  // d^CL
    float S = 0.f;
    float* base = contrib + ((size_t)bh * NC) * 4096 + kk * 64 + j;
    for (int c = 0; c < NC; c++) {
        float t = base[(size_t)c * 4096];
        base[(size_t)c * 4096] = S;
        S = __builtin_fmaf(dC, S, t);
    }
    state_out[(size_t)bh * 4096 + kk * 64 + j] = S;
}

// ---------------- recurrence: per-chunk output replay ----------------
// rgb holds r*silu(g) merged (bf16).

__global__ __launch_bounds__(256) void chunk_out(
    const unsigned short* __restrict__ kb, const unsigned short* __restrict__ vb,
    const unsigned short* __restrict__ rgb,
    const float* __restrict__ td, const float* __restrict__ tf,
    const float* __restrict__ S0, unsigned short* __restrict__ outp)
{
    const int bid = blockIdx.x;
    const int c   = bid & (NC - 1);
    const int bh  = bid >> 5;
    const int h   = bh & (NH - 1);
    const int b   = bh >> 4;
    const int tid = threadIdx.x;
    const int j   = tid >> 2;
    const int kg  = tid & 3;

    __shared__ float          kf[CL][HD];   // 32KB
    __shared__ unsigned short vs[CL][HD];   // 16KB

    const uint4* ks4 = (const uint4*)(kb + (((size_t)bh * TT) + c * CL) * HD);
    const uint4* vs4 = (const uint4*)(vb + (((size_t)bh * TT) + c * CL) * HD);
    #pragma unroll
    for (int it = 0; it < 4; ++it) {
        int ci = it * 256 + tid;
        uint4 r = ks4[ci];
        int row = ci >> 3, cb2 = (ci & 7) * 8;
        f32x4 lo = { bfu(r.x), bfu(r.x >> 16), bfu(r.y), bfu(r.y >> 16) };
        f32x4 hi = { bfu(r.z), bfu(r.z >> 16), bfu(r.w), bfu(r.w >> 16) };
        *(f32x4*)&kf[row][cb2]     = lo;
        *(f32x4*)&kf[row][cb2 + 4] = hi;
        ((uint4*)vs)[ci] = vs4[ci];
    }
    float dreg[16], st[16];
    #pragma unroll
    for (int kk = 0; kk < 16; kk++) {
        dreg[kk] = __expf(-td[h * HD + kg * 16 + kk]);
        st[kk] = S0[(size_t)bid * 4096 + (kg * 16 + kk) * 64 + j];
    }
    const float tfj = tf[h * HD + j];
    __syncthreads();

    const unsigned short* rrow = rgb + ((size_t)bh * TT + c * CL) * HD + j;
    unsigned short*       orow = outp + ((size_t)b * TT + c * CL) * DIM + h * HD + j;

    for (int i = 0; i < CL; i++) {
        const float vv = bfu(vs[i][j]);
        const float kj = kf[i][j];
        const float* krow = &kf[i][kg * 16];
        float a0 = 0.f, a1 = 0.f, a2 = 0.f, a3 = 0.f;
        #pragma unroll
        for (int q = 0; q < 4; q++) {
            f32x4 kv = *(const f32x4*)&krow[q * 4];
            float s0 = __builtin_fmaf(dreg[q*4+0], st[q*4+0], kv.x * vv);
            float s1 = __builtin_fmaf(dreg[q*4+1], st[q*4+1], kv.y * vv);
            float s2 = __builtin_fmaf(dreg[q*4+2], st[q*4+2], kv.z * vv);
            float s3 = __builtin_fmaf(dreg[q*4+3], st[q*4+3], kv.w * vv);
            st[q*4+0] = s0; st[q*4+1] = s1; st[q*4+2] = s2; st[q*4+3] = s3;
            a0 = __builtin_fmaf(kv.x, s0, a0);
            a1 = __builtin_fmaf(kv.y, s1, a1);
            a2 = __builtin_fmaf(kv.z, s2, a2);
            a3 = __builtin_fmaf(kv.w, s3, a3);
        }
        float a = (a0 + a1) + (a2 + a3);
        a += __shfl_xor(a, 1, 64);
        a += __shfl_xor(a, 2, 64);
        if (kg == 0) {
            float wkv = a + tfj * kj * vv;
            float rr = bfu(rrow[(size_t)i * HD]);
            orow[(size_t)i * DIM] = f2bf(rr * wkv);
        }
    }
}

// ---------------- launch ----------------
// Workspace map (bytes), peak 170 MB:
//   [0,32M)      xx (bf16)       -> reused as outp (bf16) after gemm1
//   [32M,40M)    wcat (bf16)
//   [40M,42M)    wob (bf16)
//   [42M,74M)    kb
//   [74M,106M)   vb
//   [106M,138M)  rb (-> r*silu(g) after rg_merge)
//   [138M,170M)  gb (bf16) -> reused as ctr (f32, 32MB) after rg_merge

static const size_t OFF_XX   = 0;
static const size_t OFF_WCAT = 33554432;
static const size_t OFF_WO   = 41943040;
static const size_t OFF_K    = 44040192;
static const size_t OFF_V    = 77594624;
static const size_t OFF_R    = 111149056;
static const size_t OFF_G    = 144703488;   // also ctr
static const size_t OFF_OP   = 0;           // aliases xx

extern "C" void kernel_launch(void* const* d_in, const int* in_sizes, int n_in,
                              void* d_out, int out_size, void* d_ws, size_t ws_size,
                              hipStream_t stream) {
    const float* x   = (const float*)d_in[0];
    const float* tmx = (const float*)d_in[1];
    const float* td  = (const float*)d_in[2];
    const float* tf  = (const float*)d_in[3];
    const float* Wk  = (const float*)d_in[4];
    const float* Wv  = (const float*)d_in[5];
    const float* Wr  = (const float*)d_in[6];
    const float* Wg  = (const float*)d_in[7];
    const float* Wo  = (const float*)d_in[8];

    char* ws = (char*)d_ws;
    unsigned short* xx   = (unsigned short*)(ws + OFF_XX);
    unsigned short* wcat = (unsigned short*)(ws + OFF_WCAT);
    unsigned short* wob  = (unsigned short*)(ws + OFF_WO);
    unsigned short* kb   = (unsigned short*)(ws + OFF_K);
    unsigned short* vb   = (unsigned short*)(ws + OFF_V);
    unsigned short* rb   = (unsigned short*)(ws + OFF_R);
    unsigned short* gb   = (unsigned short*)(ws + OFF_G);
    float*          ctr  = (float*)(ws + OFF_G);
    unsigned short* outp = (unsigned short*)(ws + OFF_OP);

    float* out       = (float*)d_out;
    float* state_out = out + (size_t)BT * DIM;

    conv_x_kernel<<<16384, 256, 0, stream>>>(x, tmx, xx);
    conv_w_kernel<<<5120, 256, 0, stream>>>(Wk, Wv, Wr, Wg, Wo, wcat, wob);
    gemm_bt<0><<<dim3(32, 128), 256, 0, stream>>>(xx, wcat, nullptr,
                                                  BT, 4096, 1024, kb, vb, rb, gb);
    rg_merge<<<16384, 256, 0, stream>>>(rb, gb);
    chunk_contrib<<<64 * NC, 256, 0, stream>>>(kb, vb, td, ctr);
    chunk_scan<<<1024, 256, 0, stream>>>(ctr, td, state_out);
    chunk_out<<<64 * NC, 256, 0, stream>>>(kb, vb, rb, td, tf, ctr, outp);
    gemm_bt<1><<<dim3(8, 128), 256, 0, stream>>>(outp, wob, out,
                                                 BT, 1024, 1024,
                                                 nullptr, nullptr, nullptr, nullptr);
}

// Round 4
// 496.338 us; speedup vs baseline: 1.3014x; 1.1489x over previous
//
#include <hip/hip_runtime.h>
#include <stdint.h>

#define DIM 1024
#define NH  16
#define HD  64
#define BB  4
#define TT  4096
#define BT  (BB*TT)   // 16384
#define NC  32        // number of chunks
#define CL  128       // chunk length

typedef __bf16 bf16x8 __attribute__((ext_vector_type(8)));
typedef float  f32x4  __attribute__((ext_vector_type(4)));

__device__ __forceinline__ float bfu(unsigned int u) {
    return __uint_as_float((u & 0xffffu) << 16);
}
__device__ __forceinline__ unsigned short f2bf(float f) {
    unsigned int u = __float_as_uint(f);
    u += 0x7fffu + ((u >> 16) & 1u);
    return (unsigned short)(u >> 16);
}

__device__ __forceinline__ void gload16(const void* g, void* lds) {
    __builtin_amdgcn_global_load_lds((__attribute__((address_space(1))) void*)g,
                                     (__attribute__((address_space(3))) void*)lds,
                                     16, 0, 0);
}

// ---------------- elementwise converters ----------------

__global__ __launch_bounds__(256) void conv_x_kernel(
    const float* __restrict__ x, const float* __restrict__ tmix,
    unsigned short* __restrict__ xx)
{
    int gid = blockIdx.x * 256 + threadIdx.x;          // 4 elems per thread
    float4 xv = ((const float4*)x)[gid];
    float4 tv = ((const float4*)tmix)[gid & 255];
    uint2 o;
    o.x = (unsigned)f2bf(xv.x * tv.x) | ((unsigned)f2bf(xv.y * tv.y) << 16);
    o.y = (unsigned)f2bf(xv.z * tv.z) | ((unsigned)f2bf(xv.w * tv.w) << 16);
    ((uint2*)xx)[gid] = o;
}

__global__ __launch_bounds__(256) void conv_w_kernel(
    const float* __restrict__ Wk, const float* __restrict__ Wv,
    const float* __restrict__ Wr, const float* __restrict__ Wg,
    const float* __restrict__ Wo,
    unsigned short* __restrict__ wcat, unsigned short* __restrict__ wob)
{
    int gid = blockIdx.x * 256 + threadIdx.x;          // 0..1310719
    size_t idx = (size_t)gid * 4;
    float4 v;
    unsigned short* dst;
    if (idx < 4194304) {
        int p = (int)(idx >> 20);
        size_t loc = idx & 1048575;
        const float* src = (p == 0) ? Wk : (p == 1) ? Wv : (p == 2) ? Wr : Wg;
        v = ((const float4*)src)[loc >> 2];
        dst = wcat + idx;
    } else {
        size_t loc = idx - 4194304;
        v = ((const float4*)Wo)[loc >> 2];
        dst = wob + loc;
    }
    uint2 o;
    o.x = (unsigned)f2bf(v.x) | ((unsigned)f2bf(v.y) << 16);
    o.y = (unsigned)f2bf(v.z) | ((unsigned)f2bf(v.w) << 16);
    *(uint2*)dst = o;
}

// rg_merge: rb[i] = rb[i] * gb[i]  (g already has silu applied), in-place on rb
__global__ __launch_bounds__(256) void rg_merge(
    unsigned short* __restrict__ rb, const unsigned short* __restrict__ gb)
{
    int gid = blockIdx.x * 256 + threadIdx.x;          // 4 bf16 per thread
    uint2 rv = ((const uint2*)rb)[gid];
    uint2 gv = ((const uint2*)gb)[gid];
    uint2 o;
    o.x = (unsigned)f2bf(bfu(rv.x) * bfu(gv.x)) |
          ((unsigned)f2bf(bfu(rv.x >> 16) * bfu(gv.x >> 16)) << 16);
    o.y = (unsigned)f2bf(bfu(rv.y) * bfu(gv.y)) |
          ((unsigned)f2bf(bfu(rv.y >> 16) * bfu(gv.y >> 16)) << 16);
    ((uint2*)rb)[gid] = o;
}

// ============ 256x256 8-phase bf16 MFMA GEMM (A[M,K] * B[N,K]^T) ============
// 512 threads = 8 waves (2 M x 4 N), per-wave output 128x64.
// K-tile BK=64 split into two k-halves (kh) of 32. LDS [buf][kh][256][32] bf16,
// XOR swizzle: byte5 ^= row-bit3 (write via pre-swizzled global src, read via
// swizzled ds_read addr). Counted vmcnt(2) at ph1/ph3 only; raw s_barrier.

#define MFMAQ(accb, av, bv)                                                    \
    _Pragma("unroll") for (int mi_ = 0; mi_ < 4; ++mi_)                        \
    _Pragma("unroll") for (int ni_ = 0; ni_ < 4; ++ni_)                        \
        acc[(accb)+mi_][ni_] = __builtin_amdgcn_mfma_f32_16x16x32_bf16(        \
            av[mi_], bv[ni_], acc[(accb)+mi_][ni_], 0, 0, 0);

#define LDA4(dst, mib, kh, bi)                                                 \
    _Pragma("unroll") for (int q_ = 0; q_ < 4; ++q_)                           \
        dst[q_] = *(const bf16x8*)&As[bi][(kh)*8192 + (arow + ((mib)+q_)*16)*32 + kxu];

#define LDB4(dst, kh, bi)                                                      \
    _Pragma("unroll") for (int q_ = 0; q_ < 4; ++q_)                           \
        dst[q_] = *(const bf16x8*)&Bs[bi][(kh)*8192 + (brow + q_*16)*32 + kxu];

#define STAGE_A(nb, kh, k0e) do {                                              \
    gload16(Asrc0 + (k0e) + (kh)*32, &As[nb][(kh)*8192 + d0]);                 \
    gload16(Asrc1 + (k0e) + (kh)*32, &As[nb][(kh)*8192 + d1]); } while (0)

#define STAGE_B(nb, kh, k0e) do {                                              \
    gload16(Bsrc0 + (k0e) + (kh)*32, &Bs[nb][(kh)*8192 + d0]);                 \
    gload16(Bsrc1 + (k0e) + (kh)*32, &Bs[nb][(kh)*8192 + d1]); } while (0)

#define SBAR()  __builtin_amdgcn_s_barrier()
#define SCHED0() __builtin_amdgcn_sched_barrier(0)
#define WAIT_LGKM0() asm volatile("s_waitcnt lgkmcnt(0)" ::: "memory")
#define WAIT_VM(n)   asm volatile("s_waitcnt vmcnt(" #n ")" ::: "memory")

template<int EPI>
__global__ __launch_bounds__(512, 2) void gemm256(
    const unsigned short* __restrict__ A, const unsigned short* __restrict__ B,
    float* __restrict__ C, int M, int N, int K,
    unsigned short* __restrict__ kb, unsigned short* __restrict__ vb,
    unsigned short* __restrict__ rb, unsigned short* __restrict__ gb)
{
    __shared__ unsigned short As[2][16384];   // 64 KB
    __shared__ unsigned short Bs[2][16384];   // 64 KB

    const int tid  = threadIdx.x;
    const int lane = tid & 63;
    const int wv   = tid >> 6;
    const int wr   = wv >> 2;      // 0..1  (M)
    const int wc   = wv & 3;       // 0..3  (N)
    const int lrow = lane & 15;
    const int kseg = lane >> 4;    // 0..3

    // bijective XCD swizzle (gridDim.x % 8 == 0 for both call sites)
    const int nwg = gridDim.x;
    const int cpx = nwg >> 3;
    const int bid = blockIdx.x;
    const int wg  = (bid & 7) * cpx + (bid >> 3);
    const int nbx = N >> 8;
    const int bx = wg % nbx, by = wg / nbx;
    const size_t bm = (size_t)by * 256, bn = (size_t)bx * 256;

    // staging lane constants: seg s = l*512 + tid; r=s>>2; csrc=(s&3)^(((s>>5)&1)<<1)
    const int r0 = tid >> 2;
    const int c0 = (tid & 3) ^ (((tid >> 5) & 1) << 1);
    const int r1 = (512 + tid) >> 2;
    const int c1 = (tid & 3) ^ ((((512 + tid) >> 5) & 1) << 1);
    const unsigned short* Asrc0 = A + (bm + r0) * (size_t)K + c0 * 8;
    const unsigned short* Asrc1 = A + (bm + r1) * (size_t)K + c1 * 8;
    const unsigned short* Bsrc0 = B + (bn + r0) * (size_t)K + c0 * 8;
    const unsigned short* Bsrc1 = B + (bn + r1) * (size_t)K + c1 * 8;
    const int d0 = (tid & 448) * 8;          // ushort offset, + lane*8 by HW
    const int d1 = (512 + (tid & 448)) * 8;

    // fragment-read lane constants
    const int arow = wr * 128 + lrow;
    const int brow = wc * 64 + lrow;
    const int kxu  = ((kseg * 16) ^ ((lrow >> 3) << 5)) >> 1;  // ushort units

    f32x4 acc[8][4] = {};
    bf16x8 aP[4], aQ[4], bP[4], bQ[4];
    const int NT = K >> 6;

    // ---- prologue: stage tile0 into buf0, read kh0 frags ----
    STAGE_A(0, 0, 0); STAGE_B(0, 0, 0); STAGE_A(0, 1, 0); STAGE_B(0, 1, 0);
    WAIT_VM(4);                    // A-kh0, B-kh0 landed
    SBAR(); SCHED0();
    LDA4(aP, 0, 0, 0);             // A kh0 mi0-3
    LDB4(bP, 0, 0);                // B kh0
    SCHED0();

    for (int t = 0; t < NT; ++t) {
        const int bufc = t & 1, bufn = bufc ^ 1;
        const int k0n = (t + 1) << 6;
        const bool more = (t + 1 < NT);
        // ---- ph0: MFMA mi0-3 x kk0 ----
        SBAR();
        WAIT_LGKM0(); SCHED0();
        if (more) STAGE_A(bufn, 0, k0n);
        __builtin_amdgcn_s_setprio(1);
        MFMAQ(0, aP, bP);
        __builtin_amdgcn_s_setprio(0);
        LDA4(aQ, 4, 0, bufc);      // A kh0 mi4-7
        SCHED0();
        // ---- ph1: MFMA mi4-7 x kk0 ----
        WAIT_VM(2);                // A-kh1[t], B-kh1[t] landed
        SBAR();
        WAIT_LGKM0(); SCHED0();
        if (more) STAGE_B(bufn, 0, k0n);
        __builtin_amdgcn_s_setprio(1);
        MFMAQ(4, aQ, bP);
        __builtin_amdgcn_s_setprio(0);
        LDA4(aP, 0, 1, bufc);      // A kh1 mi0-3
        LDB4(bQ, 1, bufc);         // B kh1
        SCHED0();
        // ---- ph2: MFMA mi0-3 x kk1 ----
        SBAR();
        WAIT_LGKM0(); SCHED0();
        if (more) STAGE_A(bufn, 1, k0n);
        __builtin_amdgcn_s_setprio(1);
        MFMAQ(0, aP, bQ);
        __builtin_amdgcn_s_setprio(0);
        LDA4(aQ, 4, 1, bufc);      // A kh1 mi4-7
        SCHED0();
        // ---- ph3: MFMA mi4-7 x kk1 ----
        WAIT_VM(2);                // next-tile A-kh0, B-kh0 landed
        SBAR();
        WAIT_LGKM0(); SCHED0();
        if (more) STAGE_B(bufn, 1, k0n);
        __builtin_amdgcn_s_setprio(1);
        MFMAQ(4, aQ, bQ);
        __builtin_amdgcn_s_setprio(0);
        if (more) {
            LDA4(aP, 0, 0, bufn);  // next tile A kh0 mi0-3
            LDB4(bP, 0, bufn);     // next tile B kh0
        }
        SCHED0();
    }

    // ---- epilogue ----
    if (EPI == 0) {
        const int p = (int)(bn >> 10);       // uniform per block
        unsigned short* dst = (p == 0) ? kb : (p == 1) ? vb : (p == 2) ? rb : gb;
        #pragma unroll
        for (int mi = 0; mi < 8; ++mi) {
            const int mbase = (int)bm + wr * 128 + mi * 16 + kseg * 4;
            #pragma unroll
            for (int ni = 0; ni < 4; ++ni) {
                const int n = (int)bn + wc * 64 + ni * 16 + lrow;
                const int e = n & 1023;
                const int h = e >> 6, j = e & 63;
                #pragma unroll
                for (int ri = 0; ri < 4; ++ri) {
                    const int m = mbase + ri;
                    const int b = m >> 12, tt = m & 4095;
                    float v = acc[mi][ni][ri];
                    if (p == 3) v = v / (1.f + __expf(-v));  // silu
                    dst[(((size_t)(b * NH + h)) * TT + tt) * HD + j] = f2bf(v);
                }
            }
        }
    } else {
        #pragma unroll
        for (int mi = 0; mi < 8; ++mi) {
            const int mbase = (int)bm + wr * 128 + mi * 16 + kseg * 4;
            #pragma unroll
            for (int ni = 0; ni < 4; ++ni) {
                const int n = (int)bn + wc * 64 + ni * 16 + lrow;
                #pragma unroll
                for (int ri = 0; ri < 4; ++ri)
                    C[(size_t)(mbase + ri) * N + n] = acc[mi][ni][ri];
            }
        }
    }
}

// ---------------- recurrence (4-wave-per-chunk layout) ----------------

__global__ __launch_bounds__(256) void chunk_contrib(
    const unsigned short* __restrict__ kb, const unsigned short* __restrict__ vb,
    const float* __restrict__ td, float* __restrict__ contrib)
{
    const int bid = blockIdx.x;
    const int c   = bid & (NC - 1);
    const int bh  = bid >> 5;
    const int h   = bh & (NH - 1);
    const int tid = threadIdx.x;
    const int j   = tid >> 2;
    const int kg  = tid & 3;

    __shared__ float          kf[CL][HD];   // 32KB
    __shared__ unsigned short vs[CL][HD];   // 16KB

    const uint4* ks4 = (const uint4*)(kb + (((size_t)bh * TT) + c * CL) * HD);
    const uint4* vs4 = (const uint4*)(vb + (((size_t)bh * TT) + c * CL) * HD);
    #pragma unroll
    for (int it = 0; it < 4; ++it) {
        int ci = it * 256 + tid;             // 0..1023 uint4s
        uint4 r = ks4[ci];
        int row = ci >> 3, cb2 = (ci & 7) * 8;
        f32x4 lo = { bfu(r.x), bfu(r.x >> 16), bfu(r.y), bfu(r.y >> 16) };
        f32x4 hi = { bfu(r.z), bfu(r.z >> 16), bfu(r.w), bfu(r.w >> 16) };
        *(f32x4*)&kf[row][cb2]     = lo;
        *(f32x4*)&kf[row][cb2 + 4] = hi;
        ((uint4*)vs)[ci] = vs4[ci];
    }
    float dreg[16], st[16];
    #pragma unroll
    for (int kk = 0; kk < 16; kk++) {
        dreg[kk] = __expf(-td[h * HD + kg * 16 + kk]);
        st[kk] = 0.f;
    }
    __syncthreads();

    for (int i = 0; i < CL; i++) {
        const float vv = bfu(vs[i][j]);
        const float* krow = &kf[i][kg * 16];
        #pragma unroll
        for (int q = 0; q < 4; q++) {
            f32x4 kv = *(const f32x4*)&krow[q * 4];
            st[q*4+0] = __builtin_fmaf(dreg[q*4+0], st[q*4+0], kv.x * vv);
            st[q*4+1] = __builtin_fmaf(dreg[q*4+1], st[q*4+1], kv.y * vv);
            st[q*4+2] = __builtin_fmaf(dreg[q*4+2], st[q*4+2], kv.z * vv);
            st[q*4+3] = __builtin_fmaf(dreg[q*4+3], st[q*4+3], kv.w * vv);
        }
    }
    float* cb = contrib + (size_t)bid * 4096 + (kg * 16) * 64 + j;
    #pragma unroll
    for (int kk = 0; kk < 16; kk++) cb[kk * 64] = st[kk];
}

__global__ __launch_bounds__(256) void chunk_scan(
    float* __restrict__ contrib, const float* __restrict__ td,
    float* __restrict__ state_out)
{
    int gtid = blockIdx.x * 256 + threadIdx.x;   // 0..262143
    int j  = gtid & 63;
    int kk = (gtid >> 6) & 63;
    int bh = gtid >> 12;
    int h  = bh & (NH - 1);
    float dC = __expf(-(float)CL * td[h * HD + kk]);  // d^CL
    float S = 0.f;
    float* base = contrib + ((size_t)bh * NC) * 4096 + kk * 64 + j;
    for (int c = 0; c < NC; c++) {
        float t = base[(size_t)c * 4096];
        base[(size_t)c * 4096] = S;
        S = __builtin_fmaf(dC, S, t);
    }
    state_out[(size_t)bh * 4096 + kk * 64 + j] = S;
}

__global__ __launch_bounds__(256) void chunk_out(
    const unsigned short* __restrict__ kb, const unsigned short* __restrict__ vb,
    const unsigned short* __restrict__ rgb,
    const float* __restrict__ td, const float* __restrict__ tf,
    const float* __restrict__ S0, unsigned short* __restrict__ outp)
{
    const int bid = blockIdx.x;
    const int c   = bid & (NC - 1);
    const int bh  = bid >> 5;
    const int h   = bh & (NH - 1);
    const int b   = bh >> 4;
    const int tid = threadIdx.x;
    const int j   = tid >> 2;
    const int kg  = tid & 3;

    __shared__ float          kf[CL][HD];   // 32KB
    __shared__ unsigned short vs[CL][HD];   // 16KB

    const uint4* ks4 = (const uint4*)(kb + (((size_t)bh * TT) + c * CL) * HD);
    const uint4* vs4 = (const uint4*)(vb + (((size_t)bh * TT) + c * CL) * HD);
    #pragma unroll
    for (int it = 0; it < 4; ++it) {
        int ci = it * 256 + tid;
        uint4 r = ks4[ci];
        int row = ci >> 3, cb2 = (ci & 7) * 8;
        f32x4 lo = { bfu(r.x), bfu(r.x >> 16), bfu(r.y), bfu(r.y >> 16) };
        f32x4 hi = { bfu(r.z), bfu(r.z >> 16), bfu(r.w), bfu(r.w >> 16) };
        *(f32x4*)&kf[row][cb2]     = lo;
        *(f32x4*)&kf[row][cb2 + 4] = hi;
        ((uint4*)vs)[ci] = vs4[ci];
    }
    float dreg[16], st[16];
    #pragma unroll
    for (int kk = 0; kk < 16; kk++) {
        dreg[kk] = __expf(-td[h * HD + kg * 16 + kk]);
        st[kk] = S0[(size_t)bid * 4096 + (kg * 16 + kk) * 64 + j];
    }
    const float tfj = tf[h * HD + j];
    __syncthreads();

    const unsigned short* rrow = rgb + ((size_t)bh * TT + c * CL) * HD + j;
    unsigned short*       orow = outp + ((size_t)b * TT + c * CL) * DIM + h * HD + j;

    for (int i = 0; i < CL; i++) {
        const float vv = bfu(vs[i][j]);
        const float kj = kf[i][j];
        const float* krow = &kf[i][kg * 16];
        float a0 = 0.f, a1 = 0.f, a2 = 0.f, a3 = 0.f;
        #pragma unroll
        for (int q = 0; q < 4; q++) {
            f32x4 kv = *(const f32x4*)&krow[q * 4];
            float s0 = __builtin_fmaf(dreg[q*4+0], st[q*4+0], kv.x * vv);
            float s1 = __builtin_fmaf(dreg[q*4+1], st[q*4+1], kv.y * vv);
            float s2 = __builtin_fmaf(dreg[q*4+2], st[q*4+2], kv.z * vv);
            float s3 = __builtin_fmaf(dreg[q*4+3], st[q*4+3], kv.w * vv);
            st[q*4+0] = s0; st[q*4+1] = s1; st[q*4+2] = s2; st[q*4+3] = s3;
            a0 = __builtin_fmaf(kv.x, s0, a0);
            a1 = __builtin_fmaf(kv.y, s1, a1);
            a2 = __builtin_fmaf(kv.z, s2, a2);
            a3 = __builtin_fmaf(kv.w, s3, a3);
        }
        float a = (a0 + a1) + (a2 + a3);
        a += __shfl_xor(a, 1, 64);
        a += __shfl_xor(a, 2, 64);
        if (kg == 0) {
            float wkv = a + tfj * kj * vv;
            float rr = bfu(rrow[(size_t)i * HD]);
            orow[(size_t)i * DIM] = f2bf(rr * wkv);
        }
    }
}

// ---------------- launch ----------------
// Workspace map (bytes), peak 170 MB:
//   [0,32M)      xx (bf16)       -> reused as outp (bf16) after gemm1
//   [32M,40M)    wcat (bf16)
//   [40M,42M)    wob (bf16)
//   [42M,74M)    kb
//   [74M,106M)   vb
//   [106M,138M)  rb (-> r*silu(g) after rg_merge)
//   [138M,170M)  gb (bf16) -> reused as ctr (f32, 32MB) after rg_merge

static const size_t OFF_XX   = 0;
static const size_t OFF_WCAT = 33554432;
static const size_t OFF_WO   = 41943040;
static const size_t OFF_K    = 44040192;
static const size_t OFF_V    = 77594624;
static const size_t OFF_R    = 111149056;
static const size_t OFF_G    = 144703488;   // also ctr
static const size_t OFF_OP   = 0;           // aliases xx

extern "C" void kernel_launch(void* const* d_in, const int* in_sizes, int n_in,
                              void* d_out, int out_size, void* d_ws, size_t ws_size,
                              hipStream_t stream) {
    const float* x   = (const float*)d_in[0];
    const float* tmx = (const float*)d_in[1];
    const float* td  = (const float*)d_in[2];
    const float* tf  = (const float*)d_in[3];
    const float* Wk  = (const float*)d_in[4];
    const float* Wv  = (const float*)d_in[5];
    const float* Wr  = (const float*)d_in[6];
    const float* Wg  = (const float*)d_in[7];
    const float* Wo  = (const float*)d_in[8];

    char* ws = (char*)d_ws;
    unsigned short* xx   = (unsigned short*)(ws + OFF_XX);
    unsigned short* wcat = (unsigned short*)(ws + OFF_WCAT);
    unsigned short* wob  = (unsigned short*)(ws + OFF_WO);
    unsigned short* kb   = (unsigned short*)(ws + OFF_K);
    unsigned short* vb   = (unsigned short*)(ws + OFF_V);
    unsigned short* rb   = (unsigned short*)(ws + OFF_R);
    unsigned short* gb   = (unsigned short*)(ws + OFF_G);
    float*          ctr  = (float*)(ws + OFF_G);
    unsigned short* outp = (unsigned short*)(ws + OFF_OP);

    float* out       = (float*)d_out;
    float* state_out = out + (size_t)BT * DIM;

    conv_x_kernel<<<16384, 256, 0, stream>>>(x, tmx, xx);
    conv_w_kernel<<<5120, 256, 0, stream>>>(Wk, Wv, Wr, Wg, Wo, wcat, wob);
    gemm256<0><<<1024, 512, 0, stream>>>(xx, wcat, nullptr,
                                         BT, 4096, 1024, kb, vb, rb, gb);
    rg_merge<<<16384, 256, 0, stream>>>(rb, gb);
    chunk_contrib<<<64 * NC, 256, 0, stream>>>(kb, vb, td, ctr);
    chunk_scan<<<1024, 256, 0, stream>>>(ctr, td, state_out);
    chunk_out<<<64 * NC, 256, 0, stream>>>(kb, vb, rb, td, tf, ctr, outp);
    gemm256<1><<<256, 512, 0, stream>>>(outp, wob, out,
                                        BT, 1024, 1024,
                                        nullptr, nullptr, nullptr, nullptr);
}

// Round 5
// 462.166 us; speedup vs baseline: 1.3976x; 1.0739x over previous
//
#include <hip/hip_runtime.h>
#include <stdint.h>

#define DIM 1024
#define NH  16
#define HD  64
#define BB  4
#define TT  4096
#define BT  (BB*TT)   // 16384
#define NC  32        // number of chunks
#define CL  128       // chunk length

typedef __bf16 bf16x8 __attribute__((ext_vector_type(8)));
typedef float  f32x4  __attribute__((ext_vector_type(4)));

__device__ __forceinline__ float bfu(unsigned int u) {
    return __uint_as_float((u & 0xffffu) << 16);
}
__device__ __forceinline__ unsigned short f2bf(float f) {
    unsigned int u = __float_as_uint(f);
    u += 0x7fffu + ((u >> 16) & 1u);
    return (unsigned short)(u >> 16);
}

__device__ __forceinline__ void gload16(const void* g, void* lds) {
    __builtin_amdgcn_global_load_lds((__attribute__((address_space(1))) void*)g,
                                     (__attribute__((address_space(3))) void*)lds,
                                     16, 0, 0);
}

// ---------------- elementwise converters ----------------

__global__ __launch_bounds__(256) void conv_x_kernel(
    const float* __restrict__ x, const float* __restrict__ tmix,
    unsigned short* __restrict__ xx)
{
    int gid = blockIdx.x * 256 + threadIdx.x;          // 4 elems per thread
    float4 xv = ((const float4*)x)[gid];
    float4 tv = ((const float4*)tmix)[gid & 255];
    uint2 o;
    o.x = (unsigned)f2bf(xv.x * tv.x) | ((unsigned)f2bf(xv.y * tv.y) << 16);
    o.y = (unsigned)f2bf(xv.z * tv.z) | ((unsigned)f2bf(xv.w * tv.w) << 16);
    ((uint2*)xx)[gid] = o;
}

__global__ __launch_bounds__(256) void conv_w_kernel(
    const float* __restrict__ Wk, const float* __restrict__ Wv,
    const float* __restrict__ Wr, const float* __restrict__ Wg,
    const float* __restrict__ Wo,
    unsigned short* __restrict__ wcat, unsigned short* __restrict__ wob)
{
    int gid = blockIdx.x * 256 + threadIdx.x;          // 0..1310719
    size_t idx = (size_t)gid * 4;
    float4 v;
    unsigned short* dst;
    if (idx < 4194304) {
        int p = (int)(idx >> 20);
        size_t loc = idx & 1048575;
        const float* src = (p == 0) ? Wk : (p == 1) ? Wv : (p == 2) ? Wr : Wg;
        v = ((const float4*)src)[loc >> 2];
        dst = wcat + idx;
    } else {
        size_t loc = idx - 4194304;
        v = ((const float4*)Wo)[loc >> 2];
        dst = wob + loc;
    }
    uint2 o;
    o.x = (unsigned)f2bf(v.x) | ((unsigned)f2bf(v.y) << 16);
    o.y = (unsigned)f2bf(v.z) | ((unsigned)f2bf(v.w) << 16);
    *(uint2*)dst = o;
}

// rg_merge: rb[i] = rb[i] * gb[i]  (g already has silu applied), in-place on rb
__global__ __launch_bounds__(256) void rg_merge(
    unsigned short* __restrict__ rb, const unsigned short* __restrict__ gb)
{
    int gid = blockIdx.x * 256 + threadIdx.x;          // 4 bf16 per thread
    uint2 rv = ((const uint2*)rb)[gid];
    uint2 gv = ((const uint2*)gb)[gid];
    uint2 o;
    o.x = (unsigned)f2bf(bfu(rv.x) * bfu(gv.x)) |
          ((unsigned)f2bf(bfu(rv.x >> 16) * bfu(gv.x >> 16)) << 16);
    o.y = (unsigned)f2bf(bfu(rv.y) * bfu(gv.y)) |
          ((unsigned)f2bf(bfu(rv.y >> 16) * bfu(gv.y >> 16)) << 16);
    ((uint2*)rb)[gid] = o;
}

// ============ 256x256 8-phase bf16 MFMA GEMM (A[M,K] * B[N,K]^T) ============

#define MFMAQ(accb, av, bv)                                                    \
    _Pragma("unroll") for (int mi_ = 0; mi_ < 4; ++mi_)                        \
    _Pragma("unroll") for (int ni_ = 0; ni_ < 4; ++ni_)                        \
        acc[(accb)+mi_][ni_] = __builtin_amdgcn_mfma_f32_16x16x32_bf16(        \
            av[mi_], bv[ni_], acc[(accb)+mi_][ni_], 0, 0, 0);

#define LDA4(dst, mib, kh, bi)                                                 \
    _Pragma("unroll") for (int q_ = 0; q_ < 4; ++q_)                           \
        dst[q_] = *(const bf16x8*)&As[bi][(kh)*8192 + (arow + ((mib)+q_)*16)*32 + kxu];

#define LDB4(dst, kh, bi)                                                      \
    _Pragma("unroll") for (int q_ = 0; q_ < 4; ++q_)                           \
        dst[q_] = *(const bf16x8*)&Bs[bi][(kh)*8192 + (brow + q_*16)*32 + kxu];

#define STAGE_A(nb, kh, k0e) do {                                              \
    gload16(Asrc0 + (k0e) + (kh)*32, &As[nb][(kh)*8192 + d0]);                 \
    gload16(Asrc1 + (k0e) + (kh)*32, &As[nb][(kh)*8192 + d1]); } while (0)

#define STAGE_B(nb, kh, k0e) do {                                              \
    gload16(Bsrc0 + (k0e) + (kh)*32, &Bs[nb][(kh)*8192 + d0]);                 \
    gload16(Bsrc1 + (k0e) + (kh)*32, &Bs[nb][(kh)*8192 + d1]); } while (0)

#define SBAR()  __builtin_amdgcn_s_barrier()
#define SCHED0() __builtin_amdgcn_sched_barrier(0)
#define WAIT_LGKM0() asm volatile("s_waitcnt lgkmcnt(0)" ::: "memory")
#define WAIT_VM(n)   asm volatile("s_waitcnt vmcnt(" #n ")" ::: "memory")

template<int EPI>
__global__ __launch_bounds__(512, 2) void gemm256(
    const unsigned short* __restrict__ A, const unsigned short* __restrict__ B,
    float* __restrict__ C, int M, int N, int K,
    unsigned short* __restrict__ kb, unsigned short* __restrict__ vb,
    unsigned short* __restrict__ rb, unsigned short* __restrict__ gb)
{
    __shared__ unsigned short As[2][16384];   // 64 KB
    __shared__ unsigned short Bs[2][16384];   // 64 KB

    const int tid  = threadIdx.x;
    const int lane = tid & 63;
    const int wv   = tid >> 6;
    const int wr   = wv >> 2;      // 0..1  (M)
    const int wc   = wv & 3;       // 0..3  (N)
    const int lrow = lane & 15;
    const int kseg = lane >> 4;    // 0..3

    const int nwg = gridDim.x;
    const int cpx = nwg >> 3;
    const int bid = blockIdx.x;
    const int wg  = (bid & 7) * cpx + (bid >> 3);
    const int nbx = N >> 8;
    const int bx = wg % nbx, by = wg / nbx;
    const size_t bm = (size_t)by * 256, bn = (size_t)bx * 256;

    const int r0 = tid >> 2;
    const int c0 = (tid & 3) ^ (((tid >> 5) & 1) << 1);
    const int r1 = (512 + tid) >> 2;
    const int c1 = (tid & 3) ^ ((((512 + tid) >> 5) & 1) << 1);
    const unsigned short* Asrc0 = A + (bm + r0) * (size_t)K + c0 * 8;
    const unsigned short* Asrc1 = A + (bm + r1) * (size_t)K + c1 * 8;
    const unsigned short* Bsrc0 = B + (bn + r0) * (size_t)K + c0 * 8;
    const unsigned short* Bsrc1 = B + (bn + r1) * (size_t)K + c1 * 8;
    const int d0 = (tid & 448) * 8;
    const int d1 = (512 + (tid & 448)) * 8;

    const int arow = wr * 128 + lrow;
    const int brow = wc * 64 + lrow;
    const int kxu  = ((kseg * 16) ^ ((lrow >> 3) << 5)) >> 1;

    f32x4 acc[8][4] = {};
    bf16x8 aP[4], aQ[4], bP[4], bQ[4];
    const int NT = K >> 6;

    STAGE_A(0, 0, 0); STAGE_B(0, 0, 0); STAGE_A(0, 1, 0); STAGE_B(0, 1, 0);
    WAIT_VM(4);
    SBAR(); SCHED0();
    LDA4(aP, 0, 0, 0);
    LDB4(bP, 0, 0);
    SCHED0();

    for (int t = 0; t < NT; ++t) {
        const int bufc = t & 1, bufn = bufc ^ 1;
        const int k0n = (t + 1) << 6;
        const bool more = (t + 1 < NT);
        SBAR();
        WAIT_LGKM0(); SCHED0();
        if (more) STAGE_A(bufn, 0, k0n);
        __builtin_amdgcn_s_setprio(1);
        MFMAQ(0, aP, bP);
        __builtin_amdgcn_s_setprio(0);
        LDA4(aQ, 4, 0, bufc);
        SCHED0();
        WAIT_VM(2);
        SBAR();
        WAIT_LGKM0(); SCHED0();
        if (more) STAGE_B(bufn, 0, k0n);
        __builtin_amdgcn_s_setprio(1);
        MFMAQ(4, aQ, bP);
        __builtin_amdgcn_s_setprio(0);
        LDA4(aP, 0, 1, bufc);
        LDB4(bQ, 1, bufc);
        SCHED0();
        SBAR();
        WAIT_LGKM0(); SCHED0();
        if (more) STAGE_A(bufn, 1, k0n);
        __builtin_amdgcn_s_setprio(1);
        MFMAQ(0, aP, bQ);
        __builtin_amdgcn_s_setprio(0);
        LDA4(aQ, 4, 1, bufc);
        SCHED0();
        WAIT_VM(2);
        SBAR();
        WAIT_LGKM0(); SCHED0();
        if (more) STAGE_B(bufn, 1, k0n);
        __builtin_amdgcn_s_setprio(1);
        MFMAQ(4, aQ, bQ);
        __builtin_amdgcn_s_setprio(0);
        if (more) {
            LDA4(aP, 0, 0, bufn);
            LDB4(bP, 0, bufn);
        }
        SCHED0();
    }

    if (EPI == 0) {
        const int p = (int)(bn >> 10);
        unsigned short* dst = (p == 0) ? kb : (p == 1) ? vb : (p == 2) ? rb : gb;
        #pragma unroll
        for (int mi = 0; mi < 8; ++mi) {
            const int mbase = (int)bm + wr * 128 + mi * 16 + kseg * 4;
            #pragma unroll
            for (int ni = 0; ni < 4; ++ni) {
                const int n = (int)bn + wc * 64 + ni * 16 + lrow;
                const int e = n & 1023;
                const int h = e >> 6, j = e & 63;
                #pragma unroll
                for (int ri = 0; ri < 4; ++ri) {
                    const int m = mbase + ri;
                    const int b = m >> 12, tt = m & 4095;
                    float v = acc[mi][ni][ri];
                    if (p == 3) v = v / (1.f + __expf(-v));  // silu
                    dst[(((size_t)(b * NH + h)) * TT + tt) * HD + j] = f2bf(v);
                }
            }
        }
    } else {
        #pragma unroll
        for (int mi = 0; mi < 8; ++mi) {
            const int mbase = (int)bm + wr * 128 + mi * 16 + kseg * 4;
            #pragma unroll
            for (int ni = 0; ni < 4; ++ni) {
                const int n = (int)bn + wc * 64 + ni * 16 + lrow;
                #pragma unroll
                for (int ri = 0; ri < 4; ++ri)
                    C[(size_t)(mbase + ri) * N + n] = acc[mi][ni][ri];
            }
        }
    }
}

// ------------- fused recurrence: intra-chunk output + contrib --------------
// Block = 256 threads = one (b,h,chunk). thread -> (j = tid>>2, kg = tid&3).
// st starts at ZERO; dots give the intra-chunk part of wkv; final st is the
// chunk contribution  C_c[kk][v] = sum_s d^(CL-1-s) k_s[kk] v_s[v],
// stored v-major: contrib[bid][j*64+kk].

__global__ __launch_bounds__(256) void chunk_fused(
    const unsigned short* __restrict__ kb, const unsigned short* __restrict__ vb,
    const unsigned short* __restrict__ rgb,
    const float* __restrict__ td, const float* __restrict__ tf,
    float* __restrict__ contrib, unsigned short* __restrict__ outp)
{
    const int bid = blockIdx.x;
    const int c   = bid & (NC - 1);
    const int bh  = bid >> 5;
    const int h   = bh & (NH - 1);
    const int b   = bh >> 4;
    const int tid = threadIdx.x;
    const int j   = tid >> 2;
    const int kg  = tid & 3;

    __shared__ float          kf[CL][HD];   // 32KB
    __shared__ unsigned short vs[CL][HD];   // 16KB

    const uint4* ks4 = (const uint4*)(kb + (((size_t)bh * TT) + c * CL) * HD);
    const uint4* vs4 = (const uint4*)(vb + (((size_t)bh * TT) + c * CL) * HD);
    #pragma unroll
    for (int it = 0; it < 4; ++it) {
        int ci = it * 256 + tid;
        uint4 r = ks4[ci];
        int row = ci >> 3, cb2 = (ci & 7) * 8;
        f32x4 lo = { bfu(r.x), bfu(r.x >> 16), bfu(r.y), bfu(r.y >> 16) };
        f32x4 hi = { bfu(r.z), bfu(r.z >> 16), bfu(r.w), bfu(r.w >> 16) };
        *(f32x4*)&kf[row][cb2]     = lo;
        *(f32x4*)&kf[row][cb2 + 4] = hi;
        ((uint4*)vs)[ci] = vs4[ci];
    }
    float dreg[16], st[16];
    #pragma unroll
    for (int kk = 0; kk < 16; kk++) {
        dreg[kk] = __expf(-td[h * HD + kg * 16 + kk]);
        st[kk] = 0.f;
    }
    const float tfj = tf[h * HD + j];
    __syncthreads();

    const unsigned short* rrow = rgb + ((size_t)bh * TT + c * CL) * HD + j;
    unsigned short*       orow = outp + ((size_t)b * TT + c * CL) * DIM + h * HD + j;

    #pragma unroll 2
    for (int i = 0; i < CL; i++) {
        const float vv = bfu(vs[i][j]);
        const float kj = kf[i][j];
        const float* krow = &kf[i][kg * 16];
        float a0 = 0.f, a1 = 0.f, a2 = 0.f, a3 = 0.f;
        #pragma unroll
        for (int q = 0; q < 4; q++) {
            f32x4 kv = *(const f32x4*)&krow[q * 4];
            float s0 = __builtin_fmaf(dreg[q*4+0], st[q*4+0], kv.x * vv);
            float s1 = __builtin_fmaf(dreg[q*4+1], st[q*4+1], kv.y * vv);
            float s2 = __builtin_fmaf(dreg[q*4+2], st[q*4+2], kv.z * vv);
            float s3 = __builtin_fmaf(dreg[q*4+3], st[q*4+3], kv.w * vv);
            st[q*4+0] = s0; st[q*4+1] = s1; st[q*4+2] = s2; st[q*4+3] = s3;
            a0 = __builtin_fmaf(kv.x, s0, a0);
            a1 = __builtin_fmaf(kv.y, s1, a1);
            a2 = __builtin_fmaf(kv.z, s2, a2);
            a3 = __builtin_fmaf(kv.w, s3, a3);
        }
        float a = (a0 + a1) + (a2 + a3);
        a += __shfl_xor(a, 1, 64);
        a += __shfl_xor(a, 2, 64);
        if (kg == 0) {
            float wkv = a + tfj * kj * vv;
            float rr = bfu(rrow[(size_t)i * HD]);
            orow[(size_t)i * DIM] = f2bf(rr * wkv);
        }
    }

    float* cb = contrib + (size_t)bid * 4096 + j * 64 + kg * 16;
    #pragma unroll
    for (int q = 0; q < 4; q++)
        *(f32x4*)&cb[q * 4] = *(f32x4*)&st[q * 4];
}

// ---------------- chunk-level scan (v-major layout) ----------------
// thread owns (bh, j, kk); writes S0 (state BEFORE chunk c, transposed,
// bf16) to s0t[bid][j*64+kk]; final state (f32) to state_out[bh][kk*64+j].

__global__ __launch_bounds__(256) void chunk_scan(
    const float* __restrict__ contrib, const float* __restrict__ td,
    unsigned short* __restrict__ s0t, float* __restrict__ state_out)
{
    int gtid = blockIdx.x * 256 + threadIdx.x;   // 0..262143
    int kk = gtid & 63;
    int j  = (gtid >> 6) & 63;
    int bh = gtid >> 12;
    int h  = bh & (NH - 1);
    float dC = __expf(-(float)CL * td[h * HD + kk]);  // d^CL
    float S = 0.f;
    const float* base = contrib + ((size_t)bh * NC) * 4096 + j * 64 + kk;
    unsigned short* sb = s0t + ((size_t)bh * NC) * 4096 + j * 64 + kk;
    for (int c = 0; c < NC; c++) {
        sb[(size_t)c * 4096] = f2bf(S);
        S = __builtin_fmaf(dC, S, base[(size_t)c * 4096]);
    }
    state_out[(size_t)bh * 4096 + kk * 64 + j] = S;
}

// ---------------- inter-chunk correction (MFMA) ----------------
// out[t][h*64+v] += rg[t][v] * sum_kk k_t[kk] d[kk]^(i+1) S0[kk][v]
// = per chunk: corr^T = S0T (A, rows v) x KD (B, rows i), k-dim = kk.

__global__ __launch_bounds__(256) void chunk_corr(
    const unsigned short* __restrict__ kb, const unsigned short* __restrict__ rgb,
    const float* __restrict__ td, const unsigned short* __restrict__ s0t,
    unsigned short* __restrict__ outp)
{
    const int bid = blockIdx.x;          // bh*NC + c
    const int c   = bid & (NC - 1);
    const int bh  = bid >> 5;
    const int h   = bh & (NH - 1);
    const int b   = bh >> 4;
    const int tid = threadIdx.x;
    const int lane = tid & 63;
    const int w    = tid >> 6;

    __shared__ unsigned short kd[CL * HD];   // 16KB, XOR-swizzled rows

    // stage KD[i][kk] = k_i[kk] * exp(-(i+1)*td[kk])
    const int srow = tid >> 3;           // 0..31
    const int kk0  = (tid & 7) * 8;
    float tdv[8];
    #pragma unroll
    for (int e = 0; e < 8; e++) tdv[e] = td[h * HD + kk0 + e];
    const unsigned short* kbase = kb + ((size_t)bh * TT + (size_t)c * CL) * HD;
    #pragma unroll
    for (int it = 0; it < 4; it++) {
        const int row = it * 32 + srow;
        uint4 r = *(const uint4*)(kbase + (size_t)row * HD + kk0);
        const float fi = -(float)(row + 1);
        unsigned int rr[4] = { r.x, r.y, r.z, r.w };
        unsigned int o[4];
        #pragma unroll
        for (int q = 0; q < 4; q++) {
            float lo = bfu(rr[q])       * __expf(fi * tdv[2*q]);
            float hi = bfu(rr[q] >> 16) * __expf(fi * tdv[2*q+1]);
            o[q] = (unsigned)f2bf(lo) | ((unsigned)f2bf(hi) << 16);
        }
        *(uint4*)((char*)kd + row * 128 + ((kk0 * 2) ^ ((row & 7) << 4))) =
            make_uint4(o[0], o[1], o[2], o[3]);
    }
    __syncthreads();

    const int lrow = lane & 15;
    const int g    = lane >> 4;

    bf16x8 afr[2][4], bfr[2][2];
    const unsigned short* sbase = s0t + (size_t)bid * 4096;
    #pragma unroll
    for (int ks = 0; ks < 2; ks++)
        #pragma unroll
        for (int vt = 0; vt < 4; vt++)
            afr[ks][vt] = *(const bf16x8*)(sbase + (vt * 16 + lrow) * 64 + g * 8 + ks * 32);
    #pragma unroll
    for (int ks = 0; ks < 2; ks++)
        #pragma unroll
        for (int bt = 0; bt < 2; bt++) {
            const int row = w * 32 + bt * 16 + lrow;
            bfr[ks][bt] = *(const bf16x8*)((const char*)kd + row * 128 +
                (((g * 8 + ks * 32) * 2) ^ ((row & 7) << 4)));
        }

    f32x4 acc[4][2] = {};
    #pragma unroll
    for (int ks = 0; ks < 2; ks++)
        #pragma unroll
        for (int vt = 0; vt < 4; vt++)
            #pragma unroll
            for (int bt = 0; bt < 2; bt++)
                acc[vt][bt] = __builtin_amdgcn_mfma_f32_16x16x32_bf16(
                    afr[ks][vt], bfr[ks][bt], acc[vt][bt], 0, 0, 0);

    // epilogue: C col = i (B-row), C rows = v (A-row)
    #pragma unroll
    for (int bt = 0; bt < 2; bt++) {
        const int i = w * 32 + bt * 16 + lrow;
        const size_t t = (size_t)c * CL + i;
        const unsigned short* rgrow = rgb + ((size_t)bh * TT + t) * HD;
        unsigned short* orow = outp + ((size_t)b * TT + t) * DIM + h * HD;
        #pragma unroll
        for (int vt = 0; vt < 4; vt++)
            #pragma unroll
            for (int ri = 0; ri < 4; ri++) {
                const int v = vt * 16 + 4 * g + ri;
                float val = bfu(orow[v]) + bfu(rgrow[v]) * acc[vt][bt][ri];
                orow[v] = f2bf(val);
            }
    }
}

// ---------------- launch ----------------
// Workspace map (bytes), peak 170 MB:
//   [0,32M)      xx (bf16)       -> reused as outp (bf16) after gemm1
//   [32M,40M)    wcat (bf16)
//   [40M,42M)    wob (bf16)
//   [42M,74M)    kb
//   [74M,106M)   vb              -> reused as s0t (bf16, 16MB) after chunk_fused
//   [106M,138M)  rb (-> r*silu(g) after rg_merge)
//   [138M,170M)  gb (bf16)       -> reused as ctr (f32, 32MB) after rg_merge

static const size_t OFF_XX   = 0;
static const size_t OFF_WCAT = 33554432;
static const size_t OFF_WO   = 41943040;
static const size_t OFF_K    = 44040192;
static const size_t OFF_V    = 77594624;
static const size_t OFF_R    = 111149056;
static const size_t OFF_G    = 144703488;   // also ctr
static const size_t OFF_OP   = 0;           // aliases xx

extern "C" void kernel_launch(void* const* d_in, const int* in_sizes, int n_in,
                              void* d_out, int out_size, void* d_ws, size_t ws_size,
                              hipStream_t stream) {
    const float* x   = (const float*)d_in[0];
    const float* tmx = (const float*)d_in[1];
    const float* td  = (const float*)d_in[2];
    const float* tf  = (const float*)d_in[3];
    const float* Wk  = (const float*)d_in[4];
    const float* Wv  = (const float*)d_in[5];
    const float* Wr  = (const float*)d_in[6];
    const float* Wg  = (const float*)d_in[7];
    const float* Wo  = (const float*)d_in[8];

    char* ws = (char*)d_ws;
    unsigned short* xx   = (unsigned short*)(ws + OFF_XX);
    unsigned short* wcat = (unsigned short*)(ws + OFF_WCAT);
    unsigned short* wob  = (unsigned short*)(ws + OFF_WO);
    unsigned short* kb   = (unsigned short*)(ws + OFF_K);
    unsigned short* vb   = (unsigned short*)(ws + OFF_V);
    unsigned short* rb   = (unsigned short*)(ws + OFF_R);
    unsigned short* gb   = (unsigned short*)(ws + OFF_G);
    float*          ctr  = (float*)(ws + OFF_G);
    unsigned short* s0t  = (unsigned short*)(ws + OFF_V);
    unsigned short* outp = (unsigned short*)(ws + OFF_OP);

    float* out       = (float*)d_out;
    float* state_out = out + (size_t)BT * DIM;

    conv_x_kernel<<<16384, 256, 0, stream>>>(x, tmx, xx);
    conv_w_kernel<<<5120, 256, 0, stream>>>(Wk, Wv, Wr, Wg, Wo, wcat, wob);
    gemm256<0><<<1024, 512, 0, stream>>>(xx, wcat, nullptr,
                                         BT, 4096, 1024, kb, vb, rb, gb);
    rg_merge<<<16384, 256, 0, stream>>>(rb, gb);
    chunk_fused<<<64 * NC, 256, 0, stream>>>(kb, vb, rb, td, tf, ctr, outp);
    chunk_scan<<<1024, 256, 0, stream>>>(ctr, td, s0t, state_out);
    chunk_corr<<<64 * NC, 256, 0, stream>>>(kb, rb, td, s0t, outp);
    gemm256<1><<<256, 512, 0, stream>>>(outp, wob, out,
                                        BT, 1024, 1024,
                                        nullptr, nullptr, nullptr, nullptr);
}

// Round 7
// 338.867 us; speedup vs baseline: 1.9061x; 1.3639x over previous
//
#include <hip/hip_runtime.h>
#include <stdint.h>

#define DIM 1024
#define NH  16
#define HD  64
#define BB  4
#define TT  4096
#define BT  (BB*TT)   // 16384
#define NC  32        // number of chunks
#define CL  128       // chunk length

typedef __bf16 bf16x8 __attribute__((ext_vector_type(8)));
typedef float  f32x4  __attribute__((ext_vector_type(4)));

__device__ __forceinline__ float bfu(unsigned int u) {
    return __uint_as_float((u & 0xffffu) << 16);
}
__device__ __forceinline__ unsigned short f2bf(float f) {
    unsigned int u = __float_as_uint(f);
    u += 0x7fffu + ((u >> 16) & 1u);
    return (unsigned short)(u >> 16);
}

__device__ __forceinline__ void gload16(const void* g, void* lds) {
    __builtin_amdgcn_global_load_lds((__attribute__((address_space(1))) void*)g,
                                     (__attribute__((address_space(3))) void*)lds,
                                     16, 0, 0);
}

// ---------------- elementwise converters ----------------

__global__ __launch_bounds__(256) void conv_x_kernel(
    const float* __restrict__ x, const float* __restrict__ tmix,
    unsigned short* __restrict__ xx)
{
    int gid = blockIdx.x * 256 + threadIdx.x;          // 4 elems per thread
    float4 xv = ((const float4*)x)[gid];
    float4 tv = ((const float4*)tmix)[gid & 255];
    uint2 o;
    o.x = (unsigned)f2bf(xv.x * tv.x) | ((unsigned)f2bf(xv.y * tv.y) << 16);
    o.y = (unsigned)f2bf(xv.z * tv.z) | ((unsigned)f2bf(xv.w * tv.w) << 16);
    ((uint2*)xx)[gid] = o;
}

__global__ __launch_bounds__(256) void conv_w_kernel(
    const float* __restrict__ Wk, const float* __restrict__ Wv,
    const float* __restrict__ Wr, const float* __restrict__ Wg,
    const float* __restrict__ Wo,
    unsigned short* __restrict__ wcat, unsigned short* __restrict__ wob)
{
    int gid = blockIdx.x * 256 + threadIdx.x;          // 0..1310719
    size_t idx = (size_t)gid * 4;
    float4 v;
    unsigned short* dst;
    if (idx < 4194304) {
        int p = (int)(idx >> 20);
        size_t loc = idx & 1048575;
        const float* src = (p == 0) ? Wk : (p == 1) ? Wv : (p == 2) ? Wr : Wg;
        v = ((const float4*)src)[loc >> 2];
        dst = wcat + idx;
    } else {
        size_t loc = idx - 4194304;
        v = ((const float4*)Wo)[loc >> 2];
        dst = wob + loc;
    }
    uint2 o;
    o.x = (unsigned)f2bf(v.x) | ((unsigned)f2bf(v.y) << 16);
    o.y = (unsigned)f2bf(v.z) | ((unsigned)f2bf(v.w) << 16);
    *(uint2*)dst = o;
}

// rg_merge: rb[i] = rb[i] * gb[i]  (g already has silu applied), in-place on rb
__global__ __launch_bounds__(256) void rg_merge(
    unsigned short* __restrict__ rb, const unsigned short* __restrict__ gb)
{
    int gid = blockIdx.x * 256 + threadIdx.x;          // 4 bf16 per thread
    uint2 rv = ((const uint2*)rb)[gid];
    uint2 gv = ((const uint2*)gb)[gid];
    uint2 o;
    o.x = (unsigned)f2bf(bfu(rv.x) * bfu(gv.x)) |
          ((unsigned)f2bf(bfu(rv.x >> 16) * bfu(gv.x >> 16)) << 16);
    o.y = (unsigned)f2bf(bfu(rv.y) * bfu(gv.y)) |
          ((unsigned)f2bf(bfu(rv.y >> 16) * bfu(gv.y >> 16)) << 16);
    ((uint2*)rb)[gid] = o;
}

// ============ 256x256 8-phase bf16 MFMA GEMM (A[M,K] * B[N,K]^T) ============

#define MFMAQ(accb, av, bv)                                                    \
    _Pragma("unroll") for (int mi_ = 0; mi_ < 4; ++mi_)                        \
    _Pragma("unroll") for (int ni_ = 0; ni_ < 4; ++ni_)                        \
        acc[(accb)+mi_][ni_] = __builtin_amdgcn_mfma_f32_16x16x32_bf16(        \
            av[mi_], bv[ni_], acc[(accb)+mi_][ni_], 0, 0, 0);

#define LDA4(dst, mib, kh, bi)                                                 \
    _Pragma("unroll") for (int q_ = 0; q_ < 4; ++q_)                           \
        dst[q_] = *(const bf16x8*)&As[bi][(kh)*8192 + (arow + ((mib)+q_)*16)*32 + kxu];

#define LDB4(dst, kh, bi)                                                      \
    _Pragma("unroll") for (int q_ = 0; q_ < 4; ++q_)                           \
        dst[q_] = *(const bf16x8*)&Bs[bi][(kh)*8192 + (brow + q_*16)*32 + kxu];

#define STAGE_A(nb, kh, k0e) do {                                              \
    gload16(Asrc0 + (k0e) + (kh)*32, &As[nb][(kh)*8192 + d0]);                 \
    gload16(Asrc1 + (k0e) + (kh)*32, &As[nb][(kh)*8192 + d1]); } while (0)

#define STAGE_B(nb, kh, k0e) do {                                              \
    gload16(Bsrc0 + (k0e) + (kh)*32, &Bs[nb][(kh)*8192 + d0]);                 \
    gload16(Bsrc1 + (k0e) + (kh)*32, &Bs[nb][(kh)*8192 + d1]); } while (0)

#define SBAR()  __builtin_amdgcn_s_barrier()
#define SCHED0() __builtin_amdgcn_sched_barrier(0)
#define WAIT_LGKM0() asm volatile("s_waitcnt lgkmcnt(0)" ::: "memory")
#define WAIT_VM(n)   asm volatile("s_waitcnt vmcnt(" #n ")" ::: "memory")

template<int EPI>
__global__ __launch_bounds__(512, 2) void gemm256(
    const unsigned short* __restrict__ A, const unsigned short* __restrict__ B,
    float* __restrict__ C, int M, int N, int K,
    unsigned short* __restrict__ kb, unsigned short* __restrict__ vb,
    unsigned short* __restrict__ rb, unsigned short* __restrict__ gb)
{
    __shared__ unsigned short As[2][16384];   // 64 KB
    __shared__ unsigned short Bs[2][16384];   // 64 KB

    const int tid  = threadIdx.x;
    const int lane = tid & 63;
    const int wv   = tid >> 6;
    const int wr   = wv >> 2;      // 0..1  (M)
    const int wc   = wv & 3;       // 0..3  (N)
    const int lrow = lane & 15;
    const int kseg = lane >> 4;    // 0..3

    const int nwg = gridDim.x;
    const int cpx = nwg >> 3;
    const int bid = blockIdx.x;
    const int wg  = (bid & 7) * cpx + (bid >> 3);
    const int nbx = N >> 8;
    const int bx = wg % nbx, by = wg / nbx;
    const size_t bm = (size_t)by * 256, bn = (size_t)bx * 256;

    const int r0 = tid >> 2;
    const int c0 = (tid & 3) ^ (((tid >> 5) & 1) << 1);
    const int r1 = (512 + tid) >> 2;
    const int c1 = (tid & 3) ^ ((((512 + tid) >> 5) & 1) << 1);
    const unsigned short* Asrc0 = A + (bm + r0) * (size_t)K + c0 * 8;
    const unsigned short* Asrc1 = A + (bm + r1) * (size_t)K + c1 * 8;
    const unsigned short* Bsrc0 = B + (bn + r0) * (size_t)K + c0 * 8;
    const unsigned short* Bsrc1 = B + (bn + r1) * (size_t)K + c1 * 8;
    const int d0 = (tid & 448) * 8;
    const int d1 = (512 + (tid & 448)) * 8;

    const int arow = wr * 128 + lrow;
    const int brow = wc * 64 + lrow;
    const int kxu  = ((kseg * 16) ^ ((lrow >> 3) << 5)) >> 1;

    f32x4 acc[8][4] = {};
    bf16x8 aP[4], aQ[4], bP[4], bQ[4];
    const int NT = K >> 6;

    STAGE_A(0, 0, 0); STAGE_B(0, 0, 0); STAGE_A(0, 1, 0); STAGE_B(0, 1, 0);
    WAIT_VM(4);
    SBAR(); SCHED0();
    LDA4(aP, 0, 0, 0);
    LDB4(bP, 0, 0);
    SCHED0();

    for (int t = 0; t < NT; ++t) {
        const int bufc = t & 1, bufn = bufc ^ 1;
        const int k0n = (t + 1) << 6;
        const bool more = (t + 1 < NT);
        SBAR();
        WAIT_LGKM0(); SCHED0();
        if (more) STAGE_A(bufn, 0, k0n);
        __builtin_amdgcn_s_setprio(1);
        MFMAQ(0, aP, bP);
        __builtin_amdgcn_s_setprio(0);
        LDA4(aQ, 4, 0, bufc);
        SCHED0();
        WAIT_VM(2);
        SBAR();
        WAIT_LGKM0(); SCHED0();
        if (more) STAGE_B(bufn, 0, k0n);
        __builtin_amdgcn_s_setprio(1);
        MFMAQ(4, aQ, bP);
        __builtin_amdgcn_s_setprio(0);
        LDA4(aP, 0, 1, bufc);
        LDB4(bQ, 1, bufc);
        SCHED0();
        SBAR();
        WAIT_LGKM0(); SCHED0();
        if (more) STAGE_A(bufn, 1, k0n);
        __builtin_amdgcn_s_setprio(1);
        MFMAQ(0, aP, bQ);
        __builtin_amdgcn_s_setprio(0);
        LDA4(aQ, 4, 1, bufc);
        SCHED0();
        WAIT_VM(2);
        SBAR();
        WAIT_LGKM0(); SCHED0();
        if (more) STAGE_B(bufn, 1, k0n);
        __builtin_amdgcn_s_setprio(1);
        MFMAQ(4, aQ, bQ);
        __builtin_amdgcn_s_setprio(0);
        if (more) {
            LDA4(aP, 0, 0, bufn);
            LDB4(bP, 0, bufn);
        }
        SCHED0();
    }

    if (EPI == 0) {
        const int p = (int)(bn >> 10);
        unsigned short* dst = (p == 0) ? kb : (p == 1) ? vb : (p == 2) ? rb : gb;
        #pragma unroll
        for (int mi = 0; mi < 8; ++mi) {
            const int mbase = (int)bm + wr * 128 + mi * 16 + kseg * 4;
            #pragma unroll
            for (int ni = 0; ni < 4; ++ni) {
                const int n = (int)bn + wc * 64 + ni * 16 + lrow;
                const int e = n & 1023;
                const int h = e >> 6, j = e & 63;
                #pragma unroll
                for (int ri = 0; ri < 4; ++ri) {
                    const int m = mbase + ri;
                    const int b = m >> 12, tt = m & 4095;
                    float v = acc[mi][ni][ri];
                    if (p == 3) v = v / (1.f + __expf(-v));  // silu
                    dst[(((size_t)(b * NH + h)) * TT + tt) * HD + j] = f2bf(v);
                }
            }
        }
    } else {
        #pragma unroll
        for (int mi = 0; mi < 8; ++mi) {
            const int mbase = (int)bm + wr * 128 + mi * 16 + kseg * 4;
            #pragma unroll
            for (int ni = 0; ni < 4; ++ni) {
                const int n = (int)bn + wc * 64 + ni * 16 + lrow;
                #pragma unroll
                for (int ri = 0; ri < 4; ++ri)
                    C[(size_t)(mbase + ri) * N + n] = acc[mi][ni][ri];
            }
        }
    }
}

// ============ MFMA chunk kernel: intra-chunk output + contrib ============
// Block = one (b,h,chunk) = 2048 blocks x 256 thr (4 waves).
// Chunk CL=128 split into 4 sub-blocks of 32. Per sub-block (local i,s in
// [0,32)): P[i][s] = sum_kk (k_i d^i)(k_s d^-s) masked s<=i;
// out_i = P@V + (k_i d^{i+1}) @ S_prev + tf.k_i.v_i;  S_new = D^32 S_prev +
// KD^T @ V (f32 accumulators, per-wave). Final S = chunk contrib -> ctr
// (v-major [j*64+kk]). Decay factors computed in f32 (single bf16 rounding).

__global__ __launch_bounds__(256) void chunk_fused(
    const unsigned short* __restrict__ kb, const unsigned short* __restrict__ vb,
    const unsigned short* __restrict__ rgb,
    const float* __restrict__ td, const float* __restrict__ tf,
    float* __restrict__ contrib, unsigned short* __restrict__ outp)
{
    __shared__ unsigned short KS [128 * 64];  // k rows [s][kk]       16KB
    __shared__ unsigned short VT [64 * 128];  // v^T [j][s], swz      16KB
    __shared__ unsigned short Qm [32 * 64];   // k_i d^i      (swz)   4KB
    __shared__ unsigned short QDm[32 * 64];   // k_i d^{i+1}  (swz)   4KB
    __shared__ unsigned short KTB[32 * 64];   // k_s d^{-s}   (swz)   4KB
    __shared__ unsigned short KDT[64 * 32];   // (k_s d^{31-s})^T swz 4KB
    __shared__ unsigned short PMt[32 * 32];   // masked P bf16 (swz)  2KB
    __shared__ unsigned short SPT[64 * 64];   // S_prev^T [j][kk] swz 8KB

    const int bid  = blockIdx.x;
    const int c    = bid & (NC - 1);
    const int bh   = bid >> 5;
    const int h    = bh & (NH - 1);
    const int batch= bh >> 4;
    const int tid  = threadIdx.x;
    const int lane = tid & 63;
    const int w    = tid >> 6;
    const int lrow = lane & 15;
    const int kseg = lane >> 4;

    const float* tdh = td + h * HD;

    // ---- stage K (row-major) and V (transposed+swizzled): 1024 uint4 each ----
    const unsigned short* kg_ = kb + ((size_t)bh * TT + (size_t)c * CL) * HD;
    const unsigned short* vg_ = vb + ((size_t)bh * TT + (size_t)c * CL) * HD;
    ((uint4*)KS)[tid]       = ((const uint4*)kg_)[tid];
    ((uint4*)KS)[tid + 256] = ((const uint4*)kg_)[tid + 256];
    ((uint4*)KS)[tid + 512] = ((const uint4*)kg_)[tid + 512];
    ((uint4*)KS)[tid + 768] = ((const uint4*)kg_)[tid + 768];
    #pragma unroll
    for (int it = 0; it < 4; ++it) {
        int ci = it * 256 + tid;            // uint4: row s=ci>>3, j0=(ci&7)*8
        uint4 r = ((const uint4*)vg_)[ci];
        int s = ci >> 3, j0 = (ci & 7) * 8;
        unsigned int vals[4] = { r.x, r.y, r.z, r.w };
        #pragma unroll
        for (int q = 0; q < 4; ++q) {
            int j1 = j0 + 2 * q, j2 = j1 + 1;
            *(unsigned short*)((char*)VT + ((j1 * 256 + s * 2) ^ ((j1 & 15) << 4)))
                = (unsigned short)(vals[q] & 0xffffu);
            *(unsigned short*)((char*)VT + ((j2 * 256 + s * 2) ^ ((j2 & 15) << 4)))
                = (unsigned short)(vals[q] >> 16);
        }
    }

    // per-thread column for the materialize phase
    const int kkc = tid & 63;
    const float t1 = tdh[kkc];

    // per-lane decay for acc_S rows (kk = 16w + kseg*4 + q)
    float e32[4];
    #pragma unroll
    for (int q = 0; q < 4; ++q)
        e32[q] = __expf(-32.f * tdh[16 * w + kseg * 4 + q]);

    const int it = w >> 1;          // P/O row-tile
    const int st = w & 1;           // P col-tile
    const int jt0 = (w & 1) * 2;    // O col-tiles {jt0, jt0+1}

    f32x4 acc_S[4] = {};            // wave w owns S rows [16w,16w+16), 4 j-tiles

    for (int sb = 0; sb < 4; ++sb) {
        const int s0 = sb * 32;
        __syncthreads();            // staging / prev-sb reads done
        // ---- materialize scaled operand matrices (f32 exp, one bf16 round) ----
        #pragma unroll
        for (int i8 = 0; i8 < 8; ++i8) {
            int r = i8 * 4 + w;     // row 0..31, fixed col kkc
            float kf  = bfu(KS[(s0 + r) * 64 + kkc]);
            float eq  = __expf(-t1 * (float)r);
            float eq1 = __expf(-t1 * (float)(r + 1));
            float ek  = __expf( t1 * (float)r);
            float ekd = __expf(-t1 * (float)(31 - r));
            int rb2 = (r * 128 + kkc * 2) ^ ((r & 7) << 4);
            *(unsigned short*)((char*)Qm  + rb2) = f2bf(kf * eq);
            *(unsigned short*)((char*)QDm + rb2) = f2bf(kf * eq1);
            *(unsigned short*)((char*)KTB + rb2) = f2bf(kf * ek);
            *(unsigned short*)((char*)KDT + ((kkc * 64 + r * 2) ^ ((kkc & 3) << 4)))
                = f2bf(kf * ekd);
        }
        __syncthreads();
        // ---- P = Q @ KTB^T (tile (it,st)), mask, store PM ----
        {
            bf16x8 qa[2], kbf[2];
            #pragma unroll
            for (int ks = 0; ks < 2; ++ks) {
                qa[ks] = *(const bf16x8*)((const char*)Qm +
                    (it * 16 + lrow) * 128 + ((kseg * 16 + ks * 64) ^ ((lrow & 7) << 4)));
                kbf[ks] = *(const bf16x8*)((const char*)KTB +
                    (st * 16 + lrow) * 128 + ((kseg * 16 + ks * 64) ^ ((lrow & 7) << 4)));
            }
            f32x4 accP = {};
            accP = __builtin_amdgcn_mfma_f32_16x16x32_bf16(qa[0], kbf[0], accP, 0, 0, 0);
            accP = __builtin_amdgcn_mfma_f32_16x16x32_bf16(qa[1], kbf[1], accP, 0, 0, 0);
            #pragma unroll
            for (int q = 0; q < 4; ++q) {
                int i_ = it * 16 + kseg * 4 + q;
                int s_ = st * 16 + lrow;
                unsigned short pv = (s_ <= i_) ? f2bf(accP[q]) : (unsigned short)0;
                *(unsigned short*)((char*)PMt + ((i_ * 64 + s_ * 2) ^ ((i_ & 3) << 4))) = pv;
            }
        }
        // ---- S update: acc_S = D^32 * acc_S + KDT @ VT ----
        {
            bf16x8 sa = *(const bf16x8*)((const char*)KDT +
                (16 * w + lrow) * 64 + ((kseg * 16) ^ ((lrow & 3) << 4)));
            #pragma unroll
            for (int jt = 0; jt < 4; ++jt) {
                #pragma unroll
                for (int q = 0; q < 4; ++q) acc_S[jt][q] *= e32[q];
                bf16x8 vbf = *(const bf16x8*)((const char*)VT +
                    (jt * 16 + lrow) * 256 + ((s0 * 2 + kseg * 16) ^ ((lrow & 15) << 4)));
                acc_S[jt] = __builtin_amdgcn_mfma_f32_16x16x32_bf16(sa, vbf, acc_S[jt], 0, 0, 0);
            }
        }
        __syncthreads();
        // ---- O = PM @ V (+ QD @ SPT) + tf-term; write outp ----
        {
            bf16x8 pa = *(const bf16x8*)((const char*)PMt +
                (it * 16 + lrow) * 64 + ((kseg * 16) ^ ((lrow & 3) << 4)));
            bf16x8 qd[2];
            #pragma unroll
            for (int ks = 0; ks < 2; ++ks)
                qd[ks] = *(const bf16x8*)((const char*)QDm +
                    (it * 16 + lrow) * 128 + ((kseg * 16 + ks * 64) ^ ((lrow & 7) << 4)));
            #pragma unroll
            for (int jj = 0; jj < 2; ++jj) {
                const int jt = jt0 + jj;
                const int j_ = jt * 16 + lrow;
                bf16x8 vbf = *(const bf16x8*)((const char*)VT +
                    j_ * 256 + ((s0 * 2 + kseg * 16) ^ ((lrow & 15) << 4)));
                f32x4 accO = {};
                accO = __builtin_amdgcn_mfma_f32_16x16x32_bf16(pa, vbf, accO, 0, 0, 0);
                if (sb > 0) {
                    #pragma unroll
                    for (int ks = 0; ks < 2; ++ks) {
                        bf16x8 sp = *(const bf16x8*)((const char*)SPT +
                            j_ * 128 + ((kseg * 16 + ks * 64) ^ ((lrow & 7) << 4)));
                        accO = __builtin_amdgcn_mfma_f32_16x16x32_bf16(qd[ks], sp, accO, 0, 0, 0);
                    }
                }
                const float tfj = tf[h * HD + j_];
                #pragma unroll
                for (int q = 0; q < 4; ++q) {
                    int ip = it * 16 + kseg * 4 + q;       // local i in sb
                    int t_ = c * CL + s0 + ip;
                    float kval = bfu(KS[(s0 + ip) * 64 + j_]);
                    float vval = bfu(*(const unsigned short*)((const char*)VT +
                        j_ * 256 + (((s0 + ip) * 2) ^ ((j_ & 15) << 4))));
                    float val = accO[q] + tfj * kval * vval;
                    float rgv = bfu(rgb[((size_t)bh * TT + t_) * HD + j_]);
                    outp[((size_t)batch * TT + t_) * DIM + h * HD + j_] = f2bf(val * rgv);
                }
            }
        }
        __syncthreads();
        // ---- publish S^T for next sub-block ----
        if (sb < 3) {
            #pragma unroll
            for (int jt = 0; jt < 4; ++jt) {
                const int j_ = jt * 16 + lrow;
                #pragma unroll
                for (int q = 0; q < 4; ++q) {
                    int kk_ = 16 * w + kseg * 4 + q;
                    *(unsigned short*)((char*)SPT +
                        ((j_ * 128 + kk_ * 2) ^ ((j_ & 7) << 4))) = f2bf(acc_S[jt][q]);
                }
            }
        }
    }

    // ---- chunk contribution (v-major, f32) ----
    float* cb = contrib + (size_t)bid * 4096;
    #pragma unroll
    for (int jt = 0; jt < 4; ++jt) {
        const int j_ = jt * 16 + lrow;
        *(f32x4*)&cb[j_ * 64 + 16 * w + kseg * 4] = acc_S[jt];
    }
}

// ---------------- chunk-level scan (v-major layout) ----------------

__global__ __launch_bounds__(256) void chunk_scan(
    const float* __restrict__ contrib, const float* __restrict__ td,
    unsigned short* __restrict__ s0t, float* __restrict__ state_out)
{
    int gtid = blockIdx.x * 256 + threadIdx.x;   // 0..262143
    int kk = gtid & 63;
    int j  = (gtid >> 6) & 63;
    int bh = gtid >> 12;
    int h  = bh & (NH - 1);
    float dC = __expf(-(float)CL * td[h * HD + kk]);  // d^CL
    float S = 0.f;
    const float* base = contrib + ((size_t)bh * NC) * 4096 + j * 64 + kk;
    unsigned short* sb = s0t + ((size_t)bh * NC) * 4096 + j * 64 + kk;
    for (int c = 0; c < NC; c++) {
        sb[(size_t)c * 4096] = f2bf(S);
        S = __builtin_fmaf(dC, S, base[(size_t)c * 4096]);
    }
    state_out[(size_t)bh * 4096 + kk * 64 + j] = S;
}

// ---------------- inter-chunk correction (MFMA) ----------------

__global__ __launch_bounds__(256) void chunk_corr(
    const unsigned short* __restrict__ kb, const unsigned short* __restrict__ rgb,
    const float* __restrict__ td, const unsigned short* __restrict__ s0t,
    unsigned short* __restrict__ outp)
{
    const int bid = blockIdx.x;          // bh*NC + c
    const int c   = bid & (NC - 1);
    const int bh  = bid >> 5;
    const int h   = bh & (NH - 1);
    const int b   = bh >> 4;
    const int tid = threadIdx.x;
    const int lane = tid & 63;
    const int w    = tid >> 6;

    __shared__ unsigned short kd[CL * HD];   // 16KB, XOR-swizzled rows

    const int srow = tid >> 3;           // 0..31
    const int kk0  = (tid & 7) * 8;
    float tdv[8];
    #pragma unroll
    for (int e = 0; e < 8; e++) tdv[e] = td[h * HD + kk0 + e];
    const unsigned short* kbase = kb + ((size_t)bh * TT + (size_t)c * CL) * HD;
    #pragma unroll
    for (int it = 0; it < 4; it++) {
        const int row = it * 32 + srow;
        uint4 r = *(const uint4*)(kbase + (size_t)row * HD + kk0);
        const float fi = -(float)(row + 1);
        unsigned int rr[4] = { r.x, r.y, r.z, r.w };
        unsigned int o[4];
        #pragma unroll
        for (int q = 0; q < 4; q++) {
            float lo = bfu(rr[q])       * __expf(fi * tdv[2*q]);
            float hi = bfu(rr[q] >> 16) * __expf(fi * tdv[2*q+1]);
            o[q] = (unsigned)f2bf(lo) | ((unsigned)f2bf(hi) << 16);
        }
        *(uint4*)((char*)kd + row * 128 + ((kk0 * 2) ^ ((row & 7) << 4))) =
            make_uint4(o[0], o[1], o[2], o[3]);
    }
    __syncthreads();

    const int lrow = lane & 15;
    const int g    = lane >> 4;

    bf16x8 afr[2][4], bfr[2][2];
    const unsigned short* sbase = s0t + (size_t)bid * 4096;
    #pragma unroll
    for (int ks = 0; ks < 2; ks++)
        #pragma unroll
        for (int vt = 0; vt < 4; vt++)
            afr[ks][vt] = *(const bf16x8*)(sbase + (vt * 16 + lrow) * 64 + g * 8 + ks * 32);
    #pragma unroll
    for (int ks = 0; ks < 2; ks++)
        #pragma unroll
        for (int bt = 0; bt < 2; bt++) {
            const int row = w * 32 + bt * 16 + lrow;
            bfr[ks][bt] = *(const bf16x8*)((const char*)kd + row * 128 +
                (((g * 8 + ks * 32) * 2) ^ ((row & 7) << 4)));
        }

    f32x4 acc[4][2] = {};
    #pragma unroll
    for (int ks = 0; ks < 2; ks++)
        #pragma unroll
        for (int vt = 0; vt < 4; vt++)
            #pragma unroll
            for (int bt = 0; bt < 2; bt++)
                acc[vt][bt] = __builtin_amdgcn_mfma_f32_16x16x32_bf16(
                    afr[ks][vt], bfr[ks][bt], acc[vt][bt], 0, 0, 0);

    #pragma unroll
    for (int bt = 0; bt < 2; bt++) {
        const int i = w * 32 + bt * 16 + lrow;
        const size_t t = (size_t)c * CL + i;
        const unsigned short* rgrow = rgb + ((size_t)bh * TT + t) * HD;
        unsigned short* orow = outp + ((size_t)b * TT + t) * DIM + h * HD;
        #pragma unroll
        for (int vt = 0; vt < 4; vt++)
            #pragma unroll
            for (int ri = 0; ri < 4; ri++) {
                const int v = vt * 16 + 4 * g + ri;
                float val = bfu(orow[v]) + bfu(rgrow[v]) * acc[vt][bt][ri];
                orow[v] = f2bf(val);
            }
    }
}

// ---------------- launch ----------------
// Workspace map (bytes), peak 170 MB:
//   [0,32M)      xx (bf16)       -> reused as outp (bf16) after gemm1
//   [32M,40M)    wcat (bf16)
//   [40M,42M)    wob (bf16)
//   [42M,74M)    kb
//   [74M,106M)   vb              -> reused as s0t (bf16, 16MB) after chunk_fused
//   [106M,138M)  rb (-> r*silu(g) after rg_merge)
//   [138M,170M)  gb (bf16)       -> reused as ctr (f32, 32MB) after rg_merge

static const size_t OFF_XX   = 0;
static const size_t OFF_WCAT = 33554432;
static const size_t OFF_WO   = 41943040;
static const size_t OFF_K    = 44040192;
static const size_t OFF_V    = 77594624;
static const size_t OFF_R    = 111149056;
static const size_t OFF_G    = 144703488;   // also ctr
static const size_t OFF_OP   = 0;           // aliases xx

extern "C" void kernel_launch(void* const* d_in, const int* in_sizes, int n_in,
                              void* d_out, int out_size, void* d_ws, size_t ws_size,
                              hipStream_t stream) {
    const float* x   = (const float*)d_in[0];
    const float* tmx = (const float*)d_in[1];
    const float* td  = (const float*)d_in[2];
    const float* tf  = (const float*)d_in[3];
    const float* Wk  = (const float*)d_in[4];
    const float* Wv  = (const float*)d_in[5];
    const float* Wr  = (const float*)d_in[6];
    const float* Wg  = (const float*)d_in[7];
    const float* Wo  = (const float*)d_in[8];

    char* ws = (char*)d_ws;
    unsigned short* xx   = (unsigned short*)(ws + OFF_XX);
    unsigned short* wcat = (unsigned short*)(ws + OFF_WCAT);
    unsigned short* wob  = (unsigned short*)(ws + OFF_WO);
    unsigned short* kb   = (unsigned short*)(ws + OFF_K);
    unsigned short* vb   = (unsigned short*)(ws + OFF_V);
    unsigned short* rb   = (unsigned short*)(ws + OFF_R);
    unsigned short* gb   = (unsigned short*)(ws + OFF_G);
    float*          ctr  = (float*)(ws + OFF_G);
    unsigned short* s0t  = (unsigned short*)(ws + OFF_V);
    unsigned short* outp = (unsigned short*)(ws + OFF_OP);

    float* out       = (float*)d_out;
    float* state_out = out + (size_t)BT * DIM;

    conv_x_kernel<<<16384, 256, 0, stream>>>(x, tmx, xx);
    conv_w_kernel<<<5120, 256, 0, stream>>>(Wk, Wv, Wr, Wg, Wo, wcat, wob);
    gemm256<0><<<1024, 512, 0, stream>>>(xx, wcat, nullptr,
                                         BT, 4096, 1024, kb, vb, rb, gb);
    rg_merge<<<16384, 256, 0, stream>>>(rb, gb);
    chunk_fused<<<64 * NC, 256, 0, stream>>>(kb, vb, rb, td, tf, ctr, outp);
    chunk_scan<<<1024, 256, 0, stream>>>(ctr, td, s0t, state_out);
    chunk_corr<<<64 * NC, 256, 0, stream>>>(kb, rb, td, s0t, outp);
    gemm256<1><<<256, 512, 0, stream>>>(outp, wob, out,
                                        BT, 1024, 1024,
                                        nullptr, nullptr, nullptr, nullptr);
}